// Round 3
// baseline (2888.672 us; speedup 1.0000x reference)
//
#include <hip/hip_runtime.h>
#include <math.h>

#define B_    32
#define T_    128
#define D_    512
#define FF_   2048
#define E_    8
#define NL_   3
#define NF_   16
#define FEAT_ 200
#define BT_   4096   // B*T

typedef short bf16x8 __attribute__((ext_vector_type(8)));
typedef float f32x4  __attribute__((ext_vector_type(4)));

__device__ inline unsigned short f2bf(float f) {
    unsigned u = __float_as_uint(f);
    unsigned r = (u + 0x7fffu + ((u >> 16) & 1u)) >> 16;   // RNE
    return (unsigned short)r;
}
// f = hi + lo + eps, |eps| <= 2^-18 |f|
__device__ inline void split_bf(float f, unsigned short& h, unsigned short& l) {
    h = f2bf(f);
    float fh = __uint_as_float(((unsigned)h) << 16);
    l = f2bf(f - fh);
}

// ---------------------------------------------------------------------------
// Split-bf16 MFMA GEMM: C = A @ Bt^T + bias, fp32-equivalent precision.
// A given as (Ah, Al) bf16 pairs [M][K]; Bt as (Bh, Bl) [N][K] (K-contig).
// Tile 128x128, BK=32, 4 waves, each 64x64 via 4x4 of 16x16x32 MFMA, 3 terms.
// MODE 0: direct rows. MODE 1: A rows via tok_list[z], C rows offsets[z]+m,
// SPLITOUT+RELU. MODE 2: A and C rows at offsets[z]+m.
// ---------------------------------------------------------------------------
template <int MODE, bool SPLITOUT, bool RELU>
__global__ __launch_bounds__(256)
void mgemm_k(const unsigned short* __restrict__ Ah, const unsigned short* __restrict__ Al,
             const unsigned short* __restrict__ Bh, const unsigned short* __restrict__ Bl,
             const float* __restrict__ bias,
             float* __restrict__ Cf, unsigned short* __restrict__ Ch,
             unsigned short* __restrict__ Cl,
             int M, int K, int N, long strB, int strBias,
             const int* __restrict__ counts, const int* __restrict__ offsets,
             const int* __restrict__ tok_list)
{
    const int z  = blockIdx.z;
    const int m0 = blockIdx.y * 128, n0 = blockIdx.x * 128;
    int rows, rowoff = 0;
    if constexpr (MODE != 0) {
        rows = counts[z];
        if (m0 >= rows) return;
        rowoff = offsets[z];
    } else {
        rows = M;
    }
    const unsigned short* Bhb = Bh + (long)z * strB;
    const unsigned short* Blb = Bl + (long)z * strB;
    const float* biasb = bias + (long)z * strBias;

    __shared__ unsigned short As[2][128 * 40];   // [hi/lo], stride 40 -> conflict-light b128
    __shared__ unsigned short Bs[2][128 * 40];

    const int tid  = threadIdx.x;
    const int wave = tid >> 6, lane = tid & 63;
    const int wm = wave & 1, wn = wave >> 1;
    const int l15 = lane & 15, quad = lane >> 4;

    // 512 16B-segments per (tile,half); 2 per thread per array
    long aoff[2], boff[2]; int soff[2];
#pragma unroll
    for (int j = 0; j < 2; ++j) {
        int linear = tid + j * 256;
        int r  = linear >> 2;
        int q8 = (linear & 3) * 8;
        long ga;
        if constexpr (MODE == 1) {
            int mg = m0 + r; if (mg >= rows) mg = rows - 1;
            ga = tok_list[z * BT_ + mg];
        } else if constexpr (MODE == 2) {
            int mg = m0 + r; if (mg >= rows) mg = rows - 1;
            ga = (long)rowoff + mg;
        } else {
            ga = m0 + r;
        }
        aoff[j] = ga * (long)K + q8;             // lda == K for all call sites
        boff[j] = (long)(n0 + r) * K + q8;
        soff[j] = r * 40 + q8;
    }

    f32x4 acc[4][4];
#pragma unroll
    for (int i = 0; i < 4; ++i)
#pragma unroll
        for (int j = 0; j < 4; ++j) acc[i][j] = (f32x4)0.f;

    for (int k0 = 0; k0 < K; k0 += 32) {
        float4 vah[2], val[2], vbh[2], vbl[2];
#pragma unroll
        for (int j = 0; j < 2; ++j) {
            vah[j] = *(const float4*)(Ah  + aoff[j] + k0);
            val[j] = *(const float4*)(Al  + aoff[j] + k0);
            vbh[j] = *(const float4*)(Bhb + boff[j] + k0);
            vbl[j] = *(const float4*)(Blb + boff[j] + k0);
        }
        __syncthreads();
#pragma unroll
        for (int j = 0; j < 2; ++j) {
            *(float4*)&As[0][soff[j]] = vah[j];
            *(float4*)&As[1][soff[j]] = val[j];
            *(float4*)&Bs[0][soff[j]] = vbh[j];
            *(float4*)&Bs[1][soff[j]] = vbl[j];
        }
        __syncthreads();

        bf16x8 ah[4], al4[4], bh4[4], bl4[4];
#pragma unroll
        for (int i = 0; i < 4; ++i) {
            int ro = (wm * 64 + i * 16 + l15) * 40 + quad * 8;
            ah[i]  = *(const bf16x8*)&As[0][ro];
            al4[i] = *(const bf16x8*)&As[1][ro];
        }
#pragma unroll
        for (int j = 0; j < 4; ++j) {
            int ro = (wn * 64 + j * 16 + l15) * 40 + quad * 8;
            bh4[j] = *(const bf16x8*)&Bs[0][ro];
            bl4[j] = *(const bf16x8*)&Bs[1][ro];
        }
#pragma unroll
        for (int i = 0; i < 4; ++i)
#pragma unroll
            for (int j = 0; j < 4; ++j) {
                acc[i][j] = __builtin_amdgcn_mfma_f32_16x16x32_bf16(al4[i], bh4[j], acc[i][j], 0, 0, 0);
                acc[i][j] = __builtin_amdgcn_mfma_f32_16x16x32_bf16(ah[i],  bl4[j], acc[i][j], 0, 0, 0);
                acc[i][j] = __builtin_amdgcn_mfma_f32_16x16x32_bf16(ah[i],  bh4[j], acc[i][j], 0, 0, 0);
            }
    }

    // C/D layout: col = lane&15, row = quad*4 + reg
#pragma unroll
    for (int i = 0; i < 4; ++i) {
#pragma unroll
        for (int r = 0; r < 4; ++r) {
            int gm = m0 + wm * 64 + i * 16 + quad * 4 + r;
            if (MODE != 0 && gm >= rows) continue;
            long crow = (MODE != 0) ? ((long)rowoff + gm) : (long)gm;
#pragma unroll
            for (int j = 0; j < 4; ++j) {
                int col = n0 + wn * 64 + j * 16 + l15;
                float v = acc[i][j][r] + biasb[col];
                if constexpr (RELU) v = fmaxf(v, 0.f);
                if constexpr (SPLITOUT) {
                    unsigned short h, l;
                    split_bf(v, h, l);
                    Ch[crow * (long)N + col] = h;
                    Cl[crow * (long)N + col] = l;
                } else {
                    Cf[crow * (long)N + col] = v;
                }
            }
        }
    }
}

// ---------------------------------------------------------------------------
// fp32 SGEMM (embed GEMM K=200, batched pb@V)
// ---------------------------------------------------------------------------
__global__ __launch_bounds__(256)
void gemm_k(const float* __restrict__ A, const float* __restrict__ Bm,
            const float* __restrict__ bias, float* __restrict__ C,
            int K, int lda, int ldb, int ldc,
            long strA, long strB, long strC, int strBias)
{
    const int z  = blockIdx.z;
    const int m0 = blockIdx.y * 64, n0 = blockIdx.x * 64;
    const float* Ab    = A    + (long)z * strA;
    const float* Bb    = Bm   + (long)z * strB;
    const float* biasb = bias + (long)z * strBias;
    float*       Cb    = C    + (long)z * strC;

    __shared__ float As[16][68];
    __shared__ float Bs[16][64];

    const int tid = threadIdx.x;
    const int tx  = tid & 15, ty = tid >> 4;
    const int ar  = tid >> 2;
    const int akc = (tid & 3) * 4;
    const float* Arow = Ab + (long)(m0 + ar) * lda;
    const int bkr = tid >> 4;
    const int bnc = (tid & 15) * 4;

    float acc[4][4];
#pragma unroll
    for (int i = 0; i < 4; ++i)
#pragma unroll
        for (int j = 0; j < 4; ++j) acc[i][j] = 0.f;

    for (int k0 = 0; k0 < K; k0 += 16) {
        if (k0 + 16 <= K) {
            float4 a = *(const float4*)(Arow + k0 + akc);
            As[akc + 0][ar] = a.x; As[akc + 1][ar] = a.y;
            As[akc + 2][ar] = a.z; As[akc + 3][ar] = a.w;
        } else {
#pragma unroll
            for (int j = 0; j < 4; ++j) {
                int kk = k0 + akc + j;
                As[akc + j][ar] = (kk < K) ? Arow[kk] : 0.f;
            }
        }
        {
            int kk = k0 + bkr;
            float4 b;
            if (kk < K) b = *(const float4*)(Bb + (long)kk * ldb + n0 + bnc);
            else        b = make_float4(0.f, 0.f, 0.f, 0.f);
            *(float4*)&Bs[bkr][bnc] = b;
        }
        __syncthreads();
#pragma unroll
        for (int k = 0; k < 16; ++k) {
            float4 av = *(const float4*)&As[k][ty * 4];
            float4 bv = *(const float4*)&Bs[k][tx * 4];
            float am[4] = {av.x, av.y, av.z, av.w};
            float bn[4] = {bv.x, bv.y, bv.z, bv.w};
#pragma unroll
            for (int i = 0; i < 4; ++i)
#pragma unroll
                for (int j = 0; j < 4; ++j)
                    acc[i][j] = fmaf(am[i], bn[j], acc[i][j]);
        }
        __syncthreads();
    }
#pragma unroll
    for (int i = 0; i < 4; ++i) {
        float*       Cp = Cb + (long)(m0 + ty * 4 + i) * ldc + n0 + tx * 4;
        const float* bp = biasb + n0 + tx * 4;
#pragma unroll
        for (int j = 0; j < 4; ++j) Cp[j] = acc[i][j] + bp[j];
    }
}

// ---------------------------------------------------------------------------
// fp32 [R][C] -> split-bf16 [C][R] (hi, lo), batched over z
// ---------------------------------------------------------------------------
__global__ __launch_bounds__(256)
void transpose_split_k(const float* __restrict__ in,
                       unsigned short* __restrict__ oh, unsigned short* __restrict__ ol,
                       int R, int C, long strIn, long strOut)
{
    __shared__ float tile[32][33];
    const float* I = in + (long)blockIdx.z * strIn;
    unsigned short* OH = oh + (long)blockIdx.z * strOut;
    unsigned short* OL = ol + (long)blockIdx.z * strOut;
    int c0 = blockIdx.x * 32, r0 = blockIdx.y * 32;
    int tx = threadIdx.x & 31, ty = threadIdx.x >> 5;
#pragma unroll
    for (int i = 0; i < 4; ++i)
        tile[ty + i * 8][tx] = I[(long)(r0 + ty + i * 8) * C + c0 + tx];
    __syncthreads();
#pragma unroll
    for (int i = 0; i < 4; ++i) {
        unsigned short h, l;
        split_bf(tile[tx][ty + i * 8], h, l);
        long o = (long)(c0 + ty + i * 8) * R + r0 + tx;
        OH[o] = h; OL[o] = l;
    }
}

__global__ void cvt_split_k(const float* __restrict__ in,
                            unsigned short* __restrict__ oh,
                            unsigned short* __restrict__ ol, int n)
{
    int i = blockIdx.x * 256 + threadIdx.x;
    if (i < n) {
        unsigned short h, l;
        split_bf(in[i], h, l);
        oh[i] = h; ol[i] = l;
    }
}

// ---------------------------------------------------------------------------
__global__ void embed_gather_k(const int* __restrict__ src,
                               const float* __restrict__ table,
                               float* __restrict__ emb)
{
    int t = blockIdx.x;
    int v = src[t];
    for (int k = threadIdx.x; k < FEAT_; k += 256)
        emb[t * FEAT_ + k] = table[v * FEAT_ + k];
}

__global__ __launch_bounds__(256)
void pb_k(const float* __restrict__ frac, const float* __restrict__ pbW,
          const float* __restrict__ pbb, const float* __restrict__ pba,
          float* __restrict__ pb)
{
    int idx = blockIdx.x * 256 + threadIdx.x;
    int b = idx >> 14;
    int i = (idx >> 7) & 127;
    int j = idx & 127;
    float diff = (frac[b * T_ + j] - frac[b * T_ + i]) * 10.0f;
    float s = 0.f;
#pragma unroll
    for (int f = 0; f < NF_; ++f)
        s = fmaf(cosf(fmaf(diff, pbW[f], pbb[f])), pba[f], s);
    pb[idx] = s;
}

__global__ __launch_bounds__(256)
void kv_k(const float* __restrict__ K, const float* __restrict__ V,
          float* __restrict__ kv)
{
    int idx = blockIdx.x * 256 + threadIdx.x;
    int b = idx >> 9, c = idx & 511;
    const float* Kp = K + (long)b * T_ * D_ + c;
    const float* Vp = V + (long)b * T_ * D_ + c;
    float s = 0.f;
    for (int t = 0; t < T_; ++t) s = fmaf(Kp[t * D_], Vp[t * D_], s);
    kv[idx] = s;
}

// LayerNorm(x + add) -> out fp32 + split bf16
__global__ __launch_bounds__(256)
void ln_res_k(const float* __restrict__ x, const float* __restrict__ add,
              const float* __restrict__ g, const float* __restrict__ b,
              float* __restrict__ out, unsigned short* __restrict__ oh,
              unsigned short* __restrict__ ol)
{
    int wave = threadIdx.x >> 6, lane = threadIdx.x & 63;
    int row = blockIdx.x * 4 + wave;
    const float* xr = x   + (long)row * D_ + lane * 8;
    const float* ar = add + (long)row * D_ + lane * 8;
    float v[8]; float s = 0.f;
#pragma unroll
    for (int j = 0; j < 8; ++j) { v[j] = xr[j] + ar[j]; s += v[j]; }
#pragma unroll
    for (int off = 32; off > 0; off >>= 1) s += __shfl_xor(s, off, 64);
    float mean = s * (1.f / D_);
    float q = 0.f;
#pragma unroll
    for (int j = 0; j < 8; ++j) { float d = v[j] - mean; q += d * d; }
#pragma unroll
    for (int off = 32; off > 0; off >>= 1) q += __shfl_xor(q, off, 64);
    float inv = rsqrtf(q * (1.f / D_) + 1e-5f);
    float* orow = out + (long)row * D_ + lane * 8;
    unsigned short* hrow = oh + (long)row * D_ + lane * 8;
    unsigned short* lrow = ol + (long)row * D_ + lane * 8;
#pragma unroll
    for (int j = 0; j < 8; ++j) {
        int c = lane * 8 + j;
        float o = (v[j] - mean) * inv * g[c] + b[c];
        orow[j] = o;
        unsigned short hh, ll;
        split_bf(o, hh, ll);
        hrow[j] = hh; lrow[j] = ll;
    }
}

// LayerNorm(x + w0*eo0 + w1*eo1) -> out fp32 + split bf16
__global__ __launch_bounds__(256)
void ln_moe_k(const float* __restrict__ x, const float* __restrict__ eo,
              const int* __restrict__ tok_slot, const float* __restrict__ tok_w,
              const int* __restrict__ offsets,
              const float* __restrict__ g, const float* __restrict__ b,
              float* __restrict__ out, unsigned short* __restrict__ oh,
              unsigned short* __restrict__ ol)
{
    int wave = threadIdx.x >> 6, lane = threadIdx.x & 63;
    int row = blockIdx.x * 4 + wave;
    int  c0 = tok_slot[row * 2], c1 = tok_slot[row * 2 + 1];
    float w0 = tok_w[row * 2],  w1 = tok_w[row * 2 + 1];
    long r0 = offsets[c0 >> 12] + (c0 & 4095);
    long r1 = offsets[c1 >> 12] + (c1 & 4095);
    const float* xr = x  + (long)row * D_ + lane * 8;
    const float* e0 = eo + r0 * D_ + lane * 8;
    const float* e1 = eo + r1 * D_ + lane * 8;
    float v[8]; float s = 0.f;
#pragma unroll
    for (int j = 0; j < 8; ++j) {
        v[j] = xr[j] + w0 * e0[j] + w1 * e1[j];
        s += v[j];
    }
#pragma unroll
    for (int off = 32; off > 0; off >>= 1) s += __shfl_xor(s, off, 64);
    float mean = s * (1.f / D_);
    float q = 0.f;
#pragma unroll
    for (int j = 0; j < 8; ++j) { float d = v[j] - mean; q += d * d; }
#pragma unroll
    for (int off = 32; off > 0; off >>= 1) q += __shfl_xor(q, off, 64);
    float inv = rsqrtf(q * (1.f / D_) + 1e-5f);
    float* orow = out + (long)row * D_ + lane * 8;
    unsigned short* hrow = oh + (long)row * D_ + lane * 8;
    unsigned short* lrow = ol + (long)row * D_ + lane * 8;
#pragma unroll
    for (int j = 0; j < 8; ++j) {
        int c = lane * 8 + j;
        float o = (v[j] - mean) * inv * g[c] + b[c];
        orow[j] = o;
        unsigned short hh, ll;
        split_bf(o, hh, ll);
        hrow[j] = hh; lrow[j] = ll;
    }
}

__global__ __launch_bounds__(256)
void gate_k(const float* __restrict__ x, const float* __restrict__ gW,
            const float* __restrict__ gb, int* __restrict__ counts,
            int* __restrict__ tok_list, int* __restrict__ tok_slot,
            float* __restrict__ tok_w)
{
    int wave = threadIdx.x >> 6, lane = threadIdx.x & 63;
    int t = blockIdx.x * 4 + wave;
    float acc[8];
#pragma unroll
    for (int e = 0; e < 8; ++e) acc[e] = 0.f;
    const float* xr = x + (long)t * D_;
#pragma unroll
    for (int j = 0; j < 8; ++j) {
        int d = lane * 8 + j;
        float xv = xr[d];
        const float* w = gW + d * 8;
#pragma unroll
        for (int e = 0; e < 8; ++e) acc[e] = fmaf(xv, w[e], acc[e]);
    }
#pragma unroll
    for (int off = 32; off > 0; off >>= 1)
#pragma unroll
        for (int e = 0; e < 8; ++e) acc[e] += __shfl_xor(acc[e], off, 64);

    if (lane == 0) {
        float m = -1e30f;
#pragma unroll
        for (int e = 0; e < 8; ++e) { acc[e] += gb[e]; m = fmaxf(m, acc[e]); }
        float p[8]; float s = 0.f;
#pragma unroll
        for (int e = 0; e < 8; ++e) { p[e] = expf(acc[e] - m); s += p[e]; }
        float inv = 1.f / s;
        int e1 = 0;
        for (int e = 1; e < 8; ++e) if (p[e] > p[e1]) e1 = e;
        int e2 = -1;
        for (int e = 0; e < 8; ++e) {
            if (e == e1) continue;
            if (e2 < 0 || p[e] > p[e2]) e2 = e;
        }
        int s1 = atomicAdd(&counts[e1], 1);
        tok_list[e1 * BT_ + s1] = t;
        tok_slot[t * 2]     = (e1 << 12) | s1;
        tok_w[t * 2]        = p[e1] * inv;
        int s2 = atomicAdd(&counts[e2], 1);
        tok_list[e2 * BT_ + s2] = t;
        tok_slot[t * 2 + 1] = (e2 << 12) | s2;
        tok_w[t * 2 + 1]    = p[e2] * inv;
    }
}

__global__ void zero_counts_k(int* __restrict__ counts)
{
    if (threadIdx.x < E_) counts[threadIdx.x] = 0;
}

__global__ void scan_k(const int* __restrict__ counts, int* __restrict__ offsets)
{
    if (threadIdx.x == 0) {
        int s = 0;
        for (int e = 0; e < E_; ++e) { offsets[e] = s; s += counts[e]; }
    }
}

// ---------------------------------------------------------------------------
extern "C" void kernel_launch(void* const* d_in, const int* in_sizes, int n_in,
                              void* d_out, int out_size, void* d_ws, size_t ws_size,
                              hipStream_t stream)
{
    const int*   src   = (const int*)  d_in[0];
    const float* frac  = (const float*)d_in[1];
    const float* table = (const float*)d_in[2];
    const float* W_m2v = (const float*)d_in[3];
    const float* b_m2v = (const float*)d_in[4];
    const float* pbW   = (const float*)d_in[5];
    const float* pbb   = (const float*)d_in[6];
    const float* pba   = (const float*)d_in[7];
    const float* Wk    = (const float*)d_in[8];
    const float* bk    = (const float*)d_in[9];
    const float* Wv    = (const float*)d_in[10];
    const float* bv    = (const float*)d_in[11];
    const float* Wo    = (const float*)d_in[12];
    const float* bo    = (const float*)d_in[13];
    const float* ln1g  = (const float*)d_in[14];
    const float* ln1b  = (const float*)d_in[15];
    const float* ln2g  = (const float*)d_in[16];
    const float* ln2b  = (const float*)d_in[17];
    const float* gW    = (const float*)d_in[18];
    const float* gb    = (const float*)d_in[19];
    const float* eW1   = (const float*)d_in[20];
    const float* eb1   = (const float*)d_in[21];
    const float* eW2   = (const float*)d_in[22];
    const float* eb2   = (const float*)d_in[23];

    // ---- workspace layout (persistent) ----
    float* ws   = (float*)d_ws;
    float* x    = ws;  ws += (long)BT_ * D_;
    float* pb   = ws;  ws += (long)B_ * T_ * T_;
    float* eo   = ws;  ws += (long)2 * BT_ * D_;
    float* kv   = ws;  ws += B_ * D_;
    float* tokw = ws;  ws += 2 * BT_;
    unsigned short* us = (unsigned short*)ws;
    unsigned short* x_h  = us;  us += (long)BT_ * D_;
    unsigned short* x_l  = us;  us += (long)BT_ * D_;
    unsigned short* Wt_h = us;  us += (long)3 * D_ * D_;
    unsigned short* Wt_l = us;  us += (long)3 * D_ * D_;
    unsigned short* e1_h = us;  us += (long)E_ * FF_ * D_;
    unsigned short* e1_l = us;  us += (long)E_ * FF_ * D_;
    unsigned short* e2_h = us;  us += (long)E_ * D_ * FF_;
    unsigned short* e2_l = us;  us += (long)E_ * D_ * FF_;
    int* counts  = (int*)us;
    int* offsets = counts + 8;
    int* toklist = offsets + 8;
    int* tokslot = toklist + E_ * BT_;
    // ---- aliased region: {emb, Kb, Vb, wv, tmp, wv pair} vs {h pair} ----
    // (h is live only between MoE GEMM1/GEMM2; the others die at LN1)
    char* ar = (char*)(tokslot + 2 * BT_);
    ar = (char*)(((size_t)ar + 15) & ~(size_t)15);
    unsigned short* h_h = (unsigned short*)ar;               // 2*BT*FF
    unsigned short* h_l = h_h + (long)2 * BT_ * FF_;
    float* emb  = (float*)ar;
    float* Kb   = emb + (long)BT_ * FEAT_;
    float* Vb   = Kb  + (long)BT_ * D_;
    float* wv   = Vb  + (long)BT_ * D_;
    float* tmp  = wv  + (long)BT_ * D_;
    unsigned short* wv_h = (unsigned short*)(tmp + (long)BT_ * D_);
    unsigned short* wv_l = wv_h + (long)BT_ * D_;

    // ---- embedder (fp32) ----
    embed_gather_k<<<BT_, 256, 0, stream>>>(src, table, emb);
    gemm_k<<<dim3(8, 64, 1), 256, 0, stream>>>(
        emb, W_m2v, b_m2v, x, FEAT_, FEAT_, D_, D_, 0, 0, 0, 0);
    cvt_split_k<<<(BT_ * D_) / 256, 256, 0, stream>>>(x, x_h, x_l, BT_ * D_);

    // ---- fourier positional bias ----
    pb_k<<<(B_ * T_ * T_) / 256, 256, 0, stream>>>(frac, pbW, pbb, pba, pb);

    for (int i = 0; i < NL_; ++i) {
        // weight transposes: fp32 [K][N] -> split bf16 [N][K]
        transpose_split_k<<<dim3(16, 16, 1), 256, 0, stream>>>(
            Wk + (long)i * D_ * D_, Wt_h + 0 * D_ * D_, Wt_l + 0 * D_ * D_,
            D_, D_, 0, 0);
        transpose_split_k<<<dim3(16, 16, 1), 256, 0, stream>>>(
            Wv + (long)i * D_ * D_, Wt_h + 1 * D_ * D_, Wt_l + 1 * D_ * D_,
            D_, D_, 0, 0);
        transpose_split_k<<<dim3(16, 16, 1), 256, 0, stream>>>(
            Wo + (long)i * D_ * D_, Wt_h + 2 * D_ * D_, Wt_l + 2 * D_ * D_,
            D_, D_, 0, 0);
        transpose_split_k<<<dim3(64, 16, E_), 256, 0, stream>>>(
            eW1 + (long)i * E_ * D_ * FF_, e1_h, e1_l, D_, FF_,
            (long)D_ * FF_, (long)FF_ * D_);
        transpose_split_k<<<dim3(16, 64, E_), 256, 0, stream>>>(
            eW2 + (long)i * E_ * FF_ * D_, e2_h, e2_l, FF_, D_,
            (long)FF_ * D_, (long)D_ * FF_);

        // K, V projections (split MFMA, fp32 out)
        mgemm_k<0, false, false><<<dim3(4, 32, 1), 256, 0, stream>>>(
            x_h, x_l, Wt_h + 0 * D_ * D_, Wt_l + 0 * D_ * D_, bk + i * D_,
            Kb, nullptr, nullptr, BT_, D_, D_, 0, 0, nullptr, nullptr, nullptr);
        mgemm_k<0, false, false><<<dim3(4, 32, 1), 256, 0, stream>>>(
            x_h, x_l, Wt_h + 1 * D_ * D_, Wt_l + 1 * D_ * D_, bv + i * D_,
            Vb, nullptr, nullptr, BT_, D_, D_, 0, 0, nullptr, nullptr, nullptr);

        kv_k<<<(B_ * D_) / 256, 256, 0, stream>>>(Kb, Vb, kv);

        // wv[b] = pb[b] @ V[b] + kv[b]  (fp32)
        gemm_k<<<dim3(8, 2, B_), 256, 0, stream>>>(
            pb, Vb, kv, wv, T_, T_, D_, D_,
            (long)T_ * T_, (long)T_ * D_, (long)T_ * D_, D_);
        cvt_split_k<<<(BT_ * D_) / 256, 256, 0, stream>>>(wv, wv_h, wv_l, BT_ * D_);

        // attention output projection
        mgemm_k<0, false, false><<<dim3(4, 32, 1), 256, 0, stream>>>(
            wv_h, wv_l, Wt_h + 2 * D_ * D_, Wt_l + 2 * D_ * D_, bo + i * D_,
            tmp, nullptr, nullptr, BT_, D_, D_, 0, 0, nullptr, nullptr, nullptr);

        // x = LN1(x + tmp)
        ln_res_k<<<BT_ / 4, 256, 0, stream>>>(x, tmp, ln1g + i * D_, ln1b + i * D_,
                                              x, x_h, x_l);

        // gating + routing
        zero_counts_k<<<1, 64, 0, stream>>>(counts);
        gate_k<<<BT_ / 4, 256, 0, stream>>>(x, gW + (long)i * D_ * E_, gb + i * E_,
                                            counts, toklist, tokslot, tokw);
        scan_k<<<1, 1, 0, stream>>>(counts, offsets);

        // MoE expert GEMMs (split MFMA)
        mgemm_k<1, true, true><<<dim3(16, 32, E_), 256, 0, stream>>>(
            x_h, x_l, e1_h, e1_l, eb1 + (long)i * E_ * FF_,
            nullptr, h_h, h_l, 0, D_, FF_,
            (long)FF_ * D_, FF_, counts, offsets, toklist);
        mgemm_k<2, false, false><<<dim3(4, 32, E_), 256, 0, stream>>>(
            h_h, h_l, e2_h, e2_l, eb2 + (long)i * E_ * D_,
            eo, nullptr, nullptr, 0, FF_, D_,
            (long)D_ * FF_, D_, counts, offsets, toklist);

        // x = LN2(x + w0*eo0 + w1*eo1)
        float* dst = (i == NL_ - 1) ? (float*)d_out : x;
        ln_moe_k<<<BT_ / 4, 256, 0, stream>>>(x, eo, tokslot, tokw, offsets,
                                              ln2g + i * D_, ln2b + i * D_,
                                              dst, x_h, x_l);
    }
}

// Round 4
// 2711.406 us; speedup vs baseline: 1.0654x; 1.0654x over previous
//
#include <hip/hip_runtime.h>
#include <math.h>

#define B_    32
#define T_    128
#define D_    512
#define FF_   2048
#define E_    8
#define NL_   3
#define NF_   16
#define FEAT_ 200
#define BT_   4096   // B*T

typedef short bf16x8 __attribute__((ext_vector_type(8)));
typedef float f32x4  __attribute__((ext_vector_type(4)));

__device__ inline unsigned short f2bf(float f) {
    unsigned u = __float_as_uint(f);
    unsigned r = (u + 0x7fffu + ((u >> 16) & 1u)) >> 16;   // RNE
    return (unsigned short)r;
}
// f = hi + lo + eps, |eps| <= 2^-18 |f|
__device__ inline void split_bf(float f, unsigned short& h, unsigned short& l) {
    h = f2bf(f);
    float fh = __uint_as_float(((unsigned)h) << 16);
    l = f2bf(f - fh);
}

// ---------------------------------------------------------------------------
// Split-bf16 MFMA GEMM with 1-deep register prefetch.
// C = A @ Bt^T + bias, fp32-equivalent precision (3-term MFMA).
// A as (Ah, Al) bf16 [M][K]; Bt as (Bh, Bl) [N][K] (K-contig).
// Tile 128x128, BK=32, 4 waves (2x2), each 64x64 via 4x4 of 16x16x32 MFMA.
// MODE 0: direct rows. MODE 1: A rows via tok_list[z], C rows offsets[z]+m.
// MODE 2: A and C rows at offsets[z]+m.
// ---------------------------------------------------------------------------
template <int MODE, bool SPLITOUT, bool RELU>
__global__ __launch_bounds__(256)
void mgemm_k(const unsigned short* __restrict__ Ah, const unsigned short* __restrict__ Al,
             const unsigned short* __restrict__ Bh, const unsigned short* __restrict__ Bl,
             const float* __restrict__ bias,
             float* __restrict__ Cf, unsigned short* __restrict__ Ch,
             unsigned short* __restrict__ Cl,
             int M, int K, int N, long strB, int strBias,
             const int* __restrict__ counts, const int* __restrict__ offsets,
             const int* __restrict__ tok_list)
{
    const int z  = blockIdx.z;
    const int m0 = blockIdx.y * 128, n0 = blockIdx.x * 128;
    int rows, rowoff = 0;
    if constexpr (MODE != 0) {
        rows = counts[z];
        if (m0 >= rows) return;
        rowoff = offsets[z];
    } else {
        rows = M;
    }
    const unsigned short* Bhb = Bh + (long)z * strB;
    const unsigned short* Blb = Bl + (long)z * strB;
    const float* biasb = bias + (long)z * strBias;

    __shared__ unsigned short As[2][128 * 40];   // [hi/lo], 80B row stride
    __shared__ unsigned short Bs[2][128 * 40];

    const int tid  = threadIdx.x;
    const int wave = tid >> 6, lane = tid & 63;
    const int wm = wave & 1, wn = wave >> 1;
    const int l15 = lane & 15, quad = lane >> 4;

    // 512 16B-segments per (tile,half); 2 per thread per array
    long aoff[2], boff[2]; int soff[2];
#pragma unroll
    for (int j = 0; j < 2; ++j) {
        int linear = tid + j * 256;
        int r  = linear >> 2;
        int q8 = (linear & 3) * 8;
        long ga;
        if constexpr (MODE == 1) {
            int mg = m0 + r; if (mg >= rows) mg = rows - 1;
            ga = tok_list[z * BT_ + mg];
        } else if constexpr (MODE == 2) {
            int mg = m0 + r; if (mg >= rows) mg = rows - 1;
            ga = (long)rowoff + mg;
        } else {
            ga = m0 + r;
        }
        aoff[j] = ga * (long)K + q8;             // lda == K at all call sites
        boff[j] = (long)(n0 + r) * K + q8;
        soff[j] = r * 40 + q8;
    }

    f32x4 acc[4][4];
#pragma unroll
    for (int i = 0; i < 4; ++i)
#pragma unroll
        for (int j = 0; j < 4; ++j) acc[i][j] = (f32x4)0.f;

    // ---- prologue: load tile 0 into registers ----
    float4 vah[2], val_[2], vbh[2], vbl[2];
#pragma unroll
    for (int j = 0; j < 2; ++j) {
        vah[j]  = *(const float4*)(Ah  + aoff[j]);
        val_[j] = *(const float4*)(Al  + aoff[j]);
        vbh[j]  = *(const float4*)(Bhb + boff[j]);
        vbl[j]  = *(const float4*)(Blb + boff[j]);
    }

    for (int k0 = 0; k0 < K; k0 += 32) {
        __syncthreads();   // prior iter's LDS reads complete
#pragma unroll
        for (int j = 0; j < 2; ++j) {
            *(float4*)&As[0][soff[j]] = vah[j];
            *(float4*)&As[1][soff[j]] = val_[j];
            *(float4*)&Bs[0][soff[j]] = vbh[j];
            *(float4*)&Bs[1][soff[j]] = vbl[j];
        }
        __syncthreads();

        // ---- issue prefetch for next iter AFTER the barrier so its vmcnt
        //      drain lands after this iter's MFMA section ----
        {
            int kn = (k0 + 32 < K) ? (k0 + 32) : k0;   // clamped (branchless)
#pragma unroll
            for (int j = 0; j < 2; ++j) {
                vah[j]  = *(const float4*)(Ah  + aoff[j] + kn);
                val_[j] = *(const float4*)(Al  + aoff[j] + kn);
                vbh[j]  = *(const float4*)(Bhb + boff[j] + kn);
                vbl[j]  = *(const float4*)(Blb + boff[j] + kn);
            }
        }

        bf16x8 ah4[4], al4[4], bh4[4], bl4[4];
#pragma unroll
        for (int i = 0; i < 4; ++i) {
            int ro = (wm * 64 + i * 16 + l15) * 40 + quad * 8;
            ah4[i] = *(const bf16x8*)&As[0][ro];
            al4[i] = *(const bf16x8*)&As[1][ro];
        }
#pragma unroll
        for (int j = 0; j < 4; ++j) {
            int ro = (wn * 64 + j * 16 + l15) * 40 + quad * 8;
            bh4[j] = *(const bf16x8*)&Bs[0][ro];
            bl4[j] = *(const bf16x8*)&Bs[1][ro];
        }
#pragma unroll
        for (int i = 0; i < 4; ++i)
#pragma unroll
            for (int j = 0; j < 4; ++j) {
                acc[i][j] = __builtin_amdgcn_mfma_f32_16x16x32_bf16(al4[i], bh4[j], acc[i][j], 0, 0, 0);
                acc[i][j] = __builtin_amdgcn_mfma_f32_16x16x32_bf16(ah4[i], bl4[j], acc[i][j], 0, 0, 0);
                acc[i][j] = __builtin_amdgcn_mfma_f32_16x16x32_bf16(ah4[i], bh4[j], acc[i][j], 0, 0, 0);
            }
    }

    // C/D layout: col = lane&15, row = quad*4 + reg
#pragma unroll
    for (int i = 0; i < 4; ++i) {
#pragma unroll
        for (int r = 0; r < 4; ++r) {
            int gm = m0 + wm * 64 + i * 16 + quad * 4 + r;
            if (MODE != 0 && gm >= rows) continue;
            long crow = (MODE != 0) ? ((long)rowoff + gm) : (long)gm;
#pragma unroll
            for (int j = 0; j < 4; ++j) {
                int col = n0 + wn * 64 + j * 16 + l15;
                float v = acc[i][j][r] + biasb[col];
                if constexpr (RELU) v = fmaxf(v, 0.f);
                if constexpr (SPLITOUT) {
                    unsigned short h, l;
                    split_bf(v, h, l);
                    Ch[crow * (long)N + col] = h;
                    Cl[crow * (long)N + col] = l;
                } else {
                    Cf[crow * (long)N + col] = v;
                }
            }
        }
    }
}

// ---------------------------------------------------------------------------
// fp32 SGEMM (embed GEMM K=200, batched pb@V)
// ---------------------------------------------------------------------------
__global__ __launch_bounds__(256)
void gemm_k(const float* __restrict__ A, const float* __restrict__ Bm,
            const float* __restrict__ bias, float* __restrict__ C,
            int K, int lda, int ldb, int ldc,
            long strA, long strB, long strC, int strBias)
{
    const int z  = blockIdx.z;
    const int m0 = blockIdx.y * 64, n0 = blockIdx.x * 64;
    const float* Ab    = A    + (long)z * strA;
    const float* Bb    = Bm   + (long)z * strB;
    const float* biasb = bias + (long)z * strBias;
    float*       Cb    = C    + (long)z * strC;

    __shared__ float As[16][68];
    __shared__ float Bs[16][64];

    const int tid = threadIdx.x;
    const int tx  = tid & 15, ty = tid >> 4;
    const int ar  = tid >> 2;
    const int akc = (tid & 3) * 4;
    const float* Arow = Ab + (long)(m0 + ar) * lda;
    const int bkr = tid >> 4;
    const int bnc = (tid & 15) * 4;

    float acc[4][4];
#pragma unroll
    for (int i = 0; i < 4; ++i)
#pragma unroll
        for (int j = 0; j < 4; ++j) acc[i][j] = 0.f;

    for (int k0 = 0; k0 < K; k0 += 16) {
        if (k0 + 16 <= K) {
            float4 a = *(const float4*)(Arow + k0 + akc);
            As[akc + 0][ar] = a.x; As[akc + 1][ar] = a.y;
            As[akc + 2][ar] = a.z; As[akc + 3][ar] = a.w;
        } else {
#pragma unroll
            for (int j = 0; j < 4; ++j) {
                int kk = k0 + akc + j;
                As[akc + j][ar] = (kk < K) ? Arow[kk] : 0.f;
            }
        }
        {
            int kk = k0 + bkr;
            float4 b;
            if (kk < K) b = *(const float4*)(Bb + (long)kk * ldb + n0 + bnc);
            else        b = make_float4(0.f, 0.f, 0.f, 0.f);
            *(float4*)&Bs[bkr][bnc] = b;
        }
        __syncthreads();
#pragma unroll
        for (int k = 0; k < 16; ++k) {
            float4 av = *(const float4*)&As[k][ty * 4];
            float4 bv = *(const float4*)&Bs[k][tx * 4];
            float am[4] = {av.x, av.y, av.z, av.w};
            float bn[4] = {bv.x, bv.y, bv.z, bv.w};
#pragma unroll
            for (int i = 0; i < 4; ++i)
#pragma unroll
                for (int j = 0; j < 4; ++j)
                    acc[i][j] = fmaf(am[i], bn[j], acc[i][j]);
        }
        __syncthreads();
    }
#pragma unroll
    for (int i = 0; i < 4; ++i) {
        float*       Cp = Cb + (long)(m0 + ty * 4 + i) * ldc + n0 + tx * 4;
        const float* bp = biasb + n0 + tx * 4;
#pragma unroll
        for (int j = 0; j < 4; ++j) Cp[j] = acc[i][j] + bp[j];
    }
}

// ---------------------------------------------------------------------------
// fp32 [R][C] -> split-bf16 [C][R] (hi, lo), batched over z
// ---------------------------------------------------------------------------
__global__ __launch_bounds__(256)
void transpose_split_k(const float* __restrict__ in,
                       unsigned short* __restrict__ oh, unsigned short* __restrict__ ol,
                       int R, int C, long strIn, long strOut)
{
    __shared__ float tile[32][33];
    const float* I = in + (long)blockIdx.z * strIn;
    unsigned short* OH = oh + (long)blockIdx.z * strOut;
    unsigned short* OL = ol + (long)blockIdx.z * strOut;
    int c0 = blockIdx.x * 32, r0 = blockIdx.y * 32;
    int tx = threadIdx.x & 31, ty = threadIdx.x >> 5;
#pragma unroll
    for (int i = 0; i < 4; ++i)
        tile[ty + i * 8][tx] = I[(long)(r0 + ty + i * 8) * C + c0 + tx];
    __syncthreads();
#pragma unroll
    for (int i = 0; i < 4; ++i) {
        unsigned short h, l;
        split_bf(tile[tx][ty + i * 8], h, l);
        long o = (long)(c0 + ty + i * 8) * R + r0 + tx;
        OH[o] = h; OL[o] = l;
    }
}

__global__ void cvt_split_k(const float* __restrict__ in,
                            unsigned short* __restrict__ oh,
                            unsigned short* __restrict__ ol, int n)
{
    int i = blockIdx.x * 256 + threadIdx.x;
    if (i < n) {
        unsigned short h, l;
        split_bf(in[i], h, l);
        oh[i] = h; ol[i] = l;
    }
}

__global__ void bias_cat_k(const float* __restrict__ a, const float* __restrict__ b,
                           float* __restrict__ o)
{
    int i = blockIdx.x * 256 + threadIdx.x;   // 1024
    o[i] = (i < D_) ? a[i] : b[i - D_];
}

// ---------------------------------------------------------------------------
__global__ void embed_gather_k(const int* __restrict__ src,
                               const float* __restrict__ table,
                               float* __restrict__ emb)
{
    int t = blockIdx.x;
    int v = src[t];
    for (int k = threadIdx.x; k < FEAT_; k += 256)
        emb[t * FEAT_ + k] = table[v * FEAT_ + k];
}

__global__ __launch_bounds__(256)
void pb_k(const float* __restrict__ frac, const float* __restrict__ pbW,
          const float* __restrict__ pbb, const float* __restrict__ pba,
          float* __restrict__ pb)
{
    int idx = blockIdx.x * 256 + threadIdx.x;
    int b = idx >> 14;
    int i = (idx >> 7) & 127;
    int j = idx & 127;
    float diff = (frac[b * T_ + j] - frac[b * T_ + i]) * 10.0f;
    float s = 0.f;
#pragma unroll
    for (int f = 0; f < NF_; ++f)
        s = fmaf(cosf(fmaf(diff, pbW[f], pbb[f])), pba[f], s);
    pb[idx] = s;
}

// kv[b,c] = sum_t K[b,t,c]*V[b,t,c]; K,V interleaved in KVb [BT][1024]
__global__ __launch_bounds__(256)
void kv_k(const float* __restrict__ KV, float* __restrict__ kv)
{
    int idx = blockIdx.x * 256 + threadIdx.x;
    int b = idx >> 9, c = idx & 511;
    const float* Kp = KV + (long)b * T_ * 1024 + c;
    float s = 0.f;
    for (int t = 0; t < T_; ++t) {
        const float* p = Kp + t * 1024;
        s = fmaf(p[0], p[D_], s);
    }
    kv[idx] = s;
}

// LayerNorm(x + add) -> out fp32 + split bf16
__global__ __launch_bounds__(256)
void ln_res_k(const float* __restrict__ x, const float* __restrict__ add,
              const float* __restrict__ g, const float* __restrict__ b,
              float* __restrict__ out, unsigned short* __restrict__ oh,
              unsigned short* __restrict__ ol)
{
    int wave = threadIdx.x >> 6, lane = threadIdx.x & 63;
    int row = blockIdx.x * 4 + wave;
    const float* xr = x   + (long)row * D_ + lane * 8;
    const float* ar = add + (long)row * D_ + lane * 8;
    float v[8]; float s = 0.f;
#pragma unroll
    for (int j = 0; j < 8; ++j) { v[j] = xr[j] + ar[j]; s += v[j]; }
#pragma unroll
    for (int off = 32; off > 0; off >>= 1) s += __shfl_xor(s, off, 64);
    float mean = s * (1.f / D_);
    float q = 0.f;
#pragma unroll
    for (int j = 0; j < 8; ++j) { float d = v[j] - mean; q += d * d; }
#pragma unroll
    for (int off = 32; off > 0; off >>= 1) q += __shfl_xor(q, off, 64);
    float inv = rsqrtf(q * (1.f / D_) + 1e-5f);
    float* orow = out + (long)row * D_ + lane * 8;
    unsigned short* hrow = oh + (long)row * D_ + lane * 8;
    unsigned short* lrow = ol + (long)row * D_ + lane * 8;
#pragma unroll
    for (int j = 0; j < 8; ++j) {
        int c = lane * 8 + j;
        float o = (v[j] - mean) * inv * g[c] + b[c];
        orow[j] = o;
        unsigned short hh, ll;
        split_bf(o, hh, ll);
        hrow[j] = hh; lrow[j] = ll;
    }
}

// LayerNorm(x + w0*eo0 + w1*eo1) -> out fp32 + split bf16
__global__ __launch_bounds__(256)
void ln_moe_k(const float* __restrict__ x, const float* __restrict__ eo,
              const int* __restrict__ tok_slot, const float* __restrict__ tok_w,
              const int* __restrict__ offsets,
              const float* __restrict__ g, const float* __restrict__ b,
              float* __restrict__ out, unsigned short* __restrict__ oh,
              unsigned short* __restrict__ ol)
{
    int wave = threadIdx.x >> 6, lane = threadIdx.x & 63;
    int row = blockIdx.x * 4 + wave;
    int  c0 = tok_slot[row * 2], c1 = tok_slot[row * 2 + 1];
    float w0 = tok_w[row * 2],  w1 = tok_w[row * 2 + 1];
    long r0 = offsets[c0 >> 12] + (c0 & 4095);
    long r1 = offsets[c1 >> 12] + (c1 & 4095);
    const float* xr = x  + (long)row * D_ + lane * 8;
    const float* e0 = eo + r0 * D_ + lane * 8;
    const float* e1 = eo + r1 * D_ + lane * 8;
    float v[8]; float s = 0.f;
#pragma unroll
    for (int j = 0; j < 8; ++j) {
        v[j] = xr[j] + w0 * e0[j] + w1 * e1[j];
        s += v[j];
    }
#pragma unroll
    for (int off = 32; off > 0; off >>= 1) s += __shfl_xor(s, off, 64);
    float mean = s * (1.f / D_);
    float q = 0.f;
#pragma unroll
    for (int j = 0; j < 8; ++j) { float d = v[j] - mean; q += d * d; }
#pragma unroll
    for (int off = 32; off > 0; off >>= 1) q += __shfl_xor(q, off, 64);
    float inv = rsqrtf(q * (1.f / D_) + 1e-5f);
    float* orow = out + (long)row * D_ + lane * 8;
    unsigned short* hrow = oh + (long)row * D_ + lane * 8;
    unsigned short* lrow = ol + (long)row * D_ + lane * 8;
#pragma unroll
    for (int j = 0; j < 8; ++j) {
        int c = lane * 8 + j;
        float o = (v[j] - mean) * inv * g[c] + b[c];
        orow[j] = o;
        unsigned short hh, ll;
        split_bf(o, hh, ll);
        hrow[j] = hh; lrow[j] = ll;
    }
}

__global__ __launch_bounds__(256)
void gate_k(const float* __restrict__ x, const float* __restrict__ gW,
            const float* __restrict__ gb, int* __restrict__ counts,
            int* __restrict__ tok_list, int* __restrict__ tok_slot,
            float* __restrict__ tok_w)
{
    int wave = threadIdx.x >> 6, lane = threadIdx.x & 63;
    int t = blockIdx.x * 4 + wave;
    float acc[8];
#pragma unroll
    for (int e = 0; e < 8; ++e) acc[e] = 0.f;
    const float* xr = x + (long)t * D_;
#pragma unroll
    for (int j = 0; j < 8; ++j) {
        int d = lane * 8 + j;
        float xv = xr[d];
        const float* w = gW + d * 8;
#pragma unroll
        for (int e = 0; e < 8; ++e) acc[e] = fmaf(xv, w[e], acc[e]);
    }
#pragma unroll
    for (int off = 32; off > 0; off >>= 1)
#pragma unroll
        for (int e = 0; e < 8; ++e) acc[e] += __shfl_xor(acc[e], off, 64);

    if (lane == 0) {
        float m = -1e30f;
#pragma unroll
        for (int e = 0; e < 8; ++e) { acc[e] += gb[e]; m = fmaxf(m, acc[e]); }
        float p[8]; float s = 0.f;
#pragma unroll
        for (int e = 0; e < 8; ++e) { p[e] = expf(acc[e] - m); s += p[e]; }
        float inv = 1.f / s;
        int e1 = 0;
        for (int e = 1; e < 8; ++e) if (p[e] > p[e1]) e1 = e;
        int e2 = -1;
        for (int e = 0; e < 8; ++e) {
            if (e == e1) continue;
            if (e2 < 0 || p[e] > p[e2]) e2 = e;
        }
        int s1 = atomicAdd(&counts[e1], 1);
        tok_list[e1 * BT_ + s1] = t;
        tok_slot[t * 2]     = (e1 << 12) | s1;
        tok_w[t * 2]        = p[e1] * inv;
        int s2 = atomicAdd(&counts[e2], 1);
        tok_list[e2 * BT_ + s2] = t;
        tok_slot[t * 2 + 1] = (e2 << 12) | s2;
        tok_w[t * 2 + 1]    = p[e2] * inv;
    }
}

__global__ void zero_counts_k(int* __restrict__ counts)
{
    if (threadIdx.x < E_) counts[threadIdx.x] = 0;
}

__global__ void scan_k(const int* __restrict__ counts, int* __restrict__ offsets)
{
    if (threadIdx.x == 0) {
        int s = 0;
        for (int e = 0; e < E_; ++e) { offsets[e] = s; s += counts[e]; }
    }
}

// ---------------------------------------------------------------------------
extern "C" void kernel_launch(void* const* d_in, const int* in_sizes, int n_in,
                              void* d_out, int out_size, void* d_ws, size_t ws_size,
                              hipStream_t stream)
{
    const int*   src   = (const int*)  d_in[0];
    const float* frac  = (const float*)d_in[1];
    const float* table = (const float*)d_in[2];
    const float* W_m2v = (const float*)d_in[3];
    const float* b_m2v = (const float*)d_in[4];
    const float* pbW   = (const float*)d_in[5];
    const float* pbb   = (const float*)d_in[6];
    const float* pba   = (const float*)d_in[7];
    const float* Wk    = (const float*)d_in[8];
    const float* bk    = (const float*)d_in[9];
    const float* Wv    = (const float*)d_in[10];
    const float* bv    = (const float*)d_in[11];
    const float* Wo    = (const float*)d_in[12];
    const float* bo    = (const float*)d_in[13];
    const float* ln1g  = (const float*)d_in[14];
    const float* ln1b  = (const float*)d_in[15];
    const float* ln2g  = (const float*)d_in[16];
    const float* ln2b  = (const float*)d_in[17];
    const float* gW    = (const float*)d_in[18];
    const float* gb    = (const float*)d_in[19];
    const float* eW1   = (const float*)d_in[20];
    const float* eb1   = (const float*)d_in[21];
    const float* eW2   = (const float*)d_in[22];
    const float* eb2   = (const float*)d_in[23];

    // ---- workspace layout (persistent) ----
    float* ws   = (float*)d_ws;
    float* x    = ws;  ws += (long)BT_ * D_;
    float* pb   = ws;  ws += (long)B_ * T_ * T_;
    float* eo   = ws;  ws += (long)2 * BT_ * D_;
    float* kv   = ws;  ws += B_ * D_;
    float* tokw = ws;  ws += 2 * BT_;
    float* kvbias = ws; ws += 2 * D_;
    unsigned short* us = (unsigned short*)ws;
    unsigned short* x_h   = us;  us += (long)BT_ * D_;
    unsigned short* x_l   = us;  us += (long)BT_ * D_;
    unsigned short* Wkv_h = us;  us += (long)2 * D_ * D_;   // [Wk^T ; Wv^T]
    unsigned short* Wkv_l = us;  us += (long)2 * D_ * D_;
    unsigned short* Wo_h  = us;  us += (long)D_ * D_;
    unsigned short* Wo_l  = us;  us += (long)D_ * D_;
    unsigned short* e1_h  = us;  us += (long)E_ * FF_ * D_;
    unsigned short* e1_l  = us;  us += (long)E_ * FF_ * D_;
    unsigned short* e2_h  = us;  us += (long)E_ * D_ * FF_;
    unsigned short* e2_l  = us;  us += (long)E_ * D_ * FF_;
    int* counts  = (int*)us;
    int* offsets = counts + 8;
    int* toklist = offsets + 8;
    int* tokslot = toklist + E_ * BT_;
    // ---- aliased region: {emb, KVb, wv, tmp, wv pair} vs {h pair} ----
    char* ar = (char*)(tokslot + 2 * BT_);
    ar = (char*)(((size_t)ar + 255) & ~(size_t)255);
    unsigned short* h_h = (unsigned short*)ar;               // [2*BT][FF]
    unsigned short* h_l = h_h + (long)2 * BT_ * FF_;
    float* emb  = (float*)ar;
    float* KVb  = emb + (long)BT_ * FEAT_;                   // [BT][1024]
    float* wv   = KVb + (long)BT_ * 2 * D_;
    float* tmp  = wv  + (long)BT_ * D_;
    unsigned short* wv_h = (unsigned short*)(tmp + (long)BT_ * D_);
    unsigned short* wv_l = wv_h + (long)BT_ * D_;

    // ---- embedder (fp32) ----
    embed_gather_k<<<BT_, 256, 0, stream>>>(src, table, emb);
    gemm_k<<<dim3(8, 64, 1), 256, 0, stream>>>(
        emb, W_m2v, b_m2v, x, FEAT_, FEAT_, D_, D_, 0, 0, 0, 0);
    cvt_split_k<<<(BT_ * D_) / 256, 256, 0, stream>>>(x, x_h, x_l, BT_ * D_);

    // ---- fourier positional bias ----
    pb_k<<<(B_ * T_ * T_) / 256, 256, 0, stream>>>(frac, pbW, pbb, pba, pb);

    for (int i = 0; i < NL_; ++i) {
        // weight transposes: fp32 [K][N] -> split bf16 [N][K]
        transpose_split_k<<<dim3(16, 16, 1), 256, 0, stream>>>(
            Wk + (long)i * D_ * D_, Wkv_h, Wkv_l, D_, D_, 0, 0);
        transpose_split_k<<<dim3(16, 16, 1), 256, 0, stream>>>(
            Wv + (long)i * D_ * D_, Wkv_h + (long)D_ * D_, Wkv_l + (long)D_ * D_,
            D_, D_, 0, 0);
        transpose_split_k<<<dim3(16, 16, 1), 256, 0, stream>>>(
            Wo + (long)i * D_ * D_, Wo_h, Wo_l, D_, D_, 0, 0);
        transpose_split_k<<<dim3(64, 16, E_), 256, 0, stream>>>(
            eW1 + (long)i * E_ * D_ * FF_, e1_h, e1_l, D_, FF_,
            (long)D_ * FF_, (long)FF_ * D_);
        transpose_split_k<<<dim3(16, 64, E_), 256, 0, stream>>>(
            eW2 + (long)i * E_ * FF_ * D_, e2_h, e2_l, FF_, D_,
            (long)FF_ * D_, (long)D_ * FF_);
        bias_cat_k<<<4, 256, 0, stream>>>(bk + i * D_, bv + i * D_, kvbias);

        // merged K|V projection: [BT][1024] = x @ [Wk Wv]
        mgemm_k<0, false, false><<<dim3(8, 32, 1), 256, 0, stream>>>(
            x_h, x_l, Wkv_h, Wkv_l, kvbias,
            KVb, nullptr, nullptr, BT_, D_, 2 * D_, 0, 0,
            nullptr, nullptr, nullptr);

        kv_k<<<(B_ * D_) / 256, 256, 0, stream>>>(KVb, kv);

        // wv[b] = pb[b] @ V[b] + kv[b]  (fp32; V = KVb cols 512..1023)
        gemm_k<<<dim3(8, 2, B_), 256, 0, stream>>>(
            pb, KVb + D_, kv, wv, T_, T_, 2 * D_, D_,
            (long)T_ * T_, (long)T_ * 2 * D_, (long)T_ * D_, D_);
        cvt_split_k<<<(BT_ * D_) / 256, 256, 0, stream>>>(wv, wv_h, wv_l, BT_ * D_);

        // attention output projection
        mgemm_k<0, false, false><<<dim3(4, 32, 1), 256, 0, stream>>>(
            wv_h, wv_l, Wo_h, Wo_l, bo + i * D_,
            tmp, nullptr, nullptr, BT_, D_, D_, 0, 0, nullptr, nullptr, nullptr);

        // x = LN1(x + tmp)
        ln_res_k<<<BT_ / 4, 256, 0, stream>>>(x, tmp, ln1g + i * D_, ln1b + i * D_,
                                              x, x_h, x_l);

        // gating + routing
        zero_counts_k<<<1, 64, 0, stream>>>(counts);
        gate_k<<<BT_ / 4, 256, 0, stream>>>(x, gW + (long)i * D_ * E_, gb + i * E_,
                                            counts, toklist, tokslot, tokw);
        scan_k<<<1, 1, 0, stream>>>(counts, offsets);

        // MoE expert GEMMs (split MFMA)
        mgemm_k<1, true, true><<<dim3(16, 32, E_), 256, 0, stream>>>(
            x_h, x_l, e1_h, e1_l, eb1 + (long)i * E_ * FF_,
            nullptr, h_h, h_l, 0, D_, FF_,
            (long)FF_ * D_, FF_, counts, offsets, toklist);
        mgemm_k<2, false, false><<<dim3(4, 32, E_), 256, 0, stream>>>(
            h_h, h_l, e2_h, e2_l, eb2 + (long)i * E_ * D_,
            eo, nullptr, nullptr, 0, FF_, D_,
            (long)D_ * FF_, D_, counts, offsets, toklist);

        // x = LN2(x + w0*eo0 + w1*eo1)
        float* dst = (i == NL_ - 1) ? (float*)d_out : x;
        ln_moe_k<<<BT_ / 4, 256, 0, stream>>>(x, eo, tokslot, tokw, offsets,
                                              ln2g + i * D_, ln2b + i * D_,
                                              dst, x_h, x_l);
    }
}

// Round 5
// 1477.723 us; speedup vs baseline: 1.9548x; 1.8349x over previous
//
#include <hip/hip_runtime.h>
#include <math.h>

#define B_    32
#define T_    128
#define D_    512
#define FF_   2048
#define E_    8
#define NL_   3
#define NF_   16
#define FEAT_ 200
#define BT_   4096   // B*T

typedef short bf16x8 __attribute__((ext_vector_type(8)));
typedef float f32x4  __attribute__((ext_vector_type(4)));

__device__ inline unsigned short f2bf(float f) {
    unsigned u = __float_as_uint(f);
    unsigned r = (u + 0x7fffu + ((u >> 16) & 1u)) >> 16;   // RNE
    return (unsigned short)r;
}
// f = hi + lo + eps, |eps| <= 2^-18 |f|
__device__ inline void split_bf(float f, unsigned short& h, unsigned short& l) {
    h = f2bf(f);
    float fh = __uint_as_float(((unsigned)h) << 16);
    l = f2bf(f - fh);
}

// async HBM->LDS DMA, 16B/lane, no VGPR round-trip. LDS dest is
// wave-uniform base + lane*16 (HW rule) -> l must be wave-uniform.
__device__ __forceinline__ void ld_g2l(const unsigned short* g, unsigned short* l)
{
    __builtin_amdgcn_global_load_lds(
        (const __attribute__((address_space(1))) unsigned int*)(uintptr_t)g,
        (__attribute__((address_space(3))) unsigned int*)(uintptr_t)l,
        16, 0, 0);
}

// ---------------------------------------------------------------------------
// Split-bf16 MFMA GEMM, global_load_lds staging (zero staging VGPRs).
// C = A @ Bt^T + bias, fp32-equivalent precision (3-term MFMA).
// A as (Ah, Al) bf16 [M][K]; Bt as (Bh, Bl) [N][K] (K-contig).
// Tile 128x128, BK=32, 4 waves (2x2), each 64x64 via 4x4 of 16x16x32 MFMA.
// LDS layout: tile row r (32 shorts = 4 x 16B segs), global seg s stored at
// pos p = s ^ ((r>>1)&3)  -> ds_read_b128 frag reads are 2-way (free).
// MODE 0: direct rows. MODE 1: A rows via tok_list[z], C rows offsets[z]+m.
// MODE 2: A and C rows at offsets[z]+m.
// ---------------------------------------------------------------------------
template <int MODE, bool SPLITOUT, bool RELU>
__global__ __launch_bounds__(256)
void mgemm_k(const unsigned short* __restrict__ Ah, const unsigned short* __restrict__ Al,
             const unsigned short* __restrict__ Bh, const unsigned short* __restrict__ Bl,
             const float* __restrict__ bias,
             float* __restrict__ Cf, unsigned short* __restrict__ Ch,
             unsigned short* __restrict__ Cl,
             int M, int K, int N, long strB, int strBias,
             const int* __restrict__ counts, const int* __restrict__ offsets,
             const int* __restrict__ tok_list)
{
    const int z  = blockIdx.z;
    const int m0 = blockIdx.y * 128, n0 = blockIdx.x * 128;
    int rows, rowoff = 0;
    if constexpr (MODE != 0) {
        rows = counts[z];
        if (m0 >= rows) return;
        rowoff = offsets[z];
    } else {
        rows = M;
    }
    const unsigned short* Bhb = Bh + (long)z * strB;
    const unsigned short* Blb = Bl + (long)z * strB;
    const float* biasb = bias + (long)z * strBias;

    // 4 x 8 KB, unpadded (DMA requires contiguous lane order)
    __shared__ unsigned short S0[128 * 32];   // A hi
    __shared__ unsigned short S1[128 * 32];   // A lo
    __shared__ unsigned short S2[128 * 32];   // B hi
    __shared__ unsigned short S3[128 * 32];   // B lo

    const int tid  = threadIdx.x;
    const int w    = tid >> 6, lane = tid & 63;
    const int wm = w & 1, wn = w >> 1;
    const int l15 = lane & 15, quad = lane >> 4;

    // ---- staging map: issue j of wave w covers linear segs L=(w*2+j)*64+lane
    //      r = L>>2 (tile row), p = lane&3 (LDS pos), global seg s = p^((r>>1)&3)
    const int lrow0 = w * 32 + (lane >> 2);          // r for issue 0
    const int lrow1 = lrow0 + 16;                    // r for issue 1
    const int sseg  = (lane & 3) ^ ((lane >> 3) & 3);
    const int lb0   = (w * 2 + 0) * 512;             // uniform LDS short-offset
    const int lb1   = (w * 2 + 1) * 512;

    long ga0, ga1;
    if constexpr (MODE == 1) {
        int m_a = m0 + lrow0; if (m_a >= rows) m_a = rows - 1;
        int m_b = m0 + lrow1; if (m_b >= rows) m_b = rows - 1;
        ga0 = tok_list[z * BT_ + m_a];
        ga1 = tok_list[z * BT_ + m_b];
    } else if constexpr (MODE == 2) {
        int m_a = m0 + lrow0; if (m_a >= rows) m_a = rows - 1;
        int m_b = m0 + lrow1; if (m_b >= rows) m_b = rows - 1;
        ga0 = (long)rowoff + m_a;
        ga1 = (long)rowoff + m_b;
    } else {
        ga0 = m0 + lrow0;
        ga1 = m0 + lrow1;
    }
    const long aoff0 = ga0 * (long)K + sseg * 8;
    const long aoff1 = ga1 * (long)K + sseg * 8;
    const long boff0 = (long)(n0 + lrow0) * K + sseg * 8;
    const long boff1 = (long)(n0 + lrow1) * K + sseg * 8;

    f32x4 acc[4][4];
#pragma unroll
    for (int i = 0; i < 4; ++i)
#pragma unroll
        for (int j = 0; j < 4; ++j) acc[i][j] = (f32x4)0.f;

    const int xq = quad ^ ((l15 >> 1) & 3);          // swizzled read pos

    for (int k0 = 0; k0 < K; k0 += 32) {
        __syncthreads();                              // prev reads done
        ld_g2l(Ah  + aoff0 + k0, S0 + lb0);
        ld_g2l(Ah  + aoff1 + k0, S0 + lb1);
        ld_g2l(Al  + aoff0 + k0, S1 + lb0);
        ld_g2l(Al  + aoff1 + k0, S1 + lb1);
        ld_g2l(Bhb + boff0 + k0, S2 + lb0);
        ld_g2l(Bhb + boff1 + k0, S2 + lb1);
        ld_g2l(Blb + boff0 + k0, S3 + lb0);
        ld_g2l(Blb + boff1 + k0, S3 + lb1);
        __syncthreads();                              // vmcnt drain + barrier

        bf16x8 ah4[4], al4[4], bh4[4], bl4[4];
#pragma unroll
        for (int i = 0; i < 4; ++i) {
            int ro = (wm * 64 + i * 16 + l15) * 32 + xq * 8;
            ah4[i] = *(const bf16x8*)&S0[ro];
            al4[i] = *(const bf16x8*)&S1[ro];
        }
#pragma unroll
        for (int j = 0; j < 4; ++j) {
            int ro = (wn * 64 + j * 16 + l15) * 32 + xq * 8;
            bh4[j] = *(const bf16x8*)&S2[ro];
            bl4[j] = *(const bf16x8*)&S3[ro];
        }
#pragma unroll
        for (int i = 0; i < 4; ++i)
#pragma unroll
            for (int j = 0; j < 4; ++j) {
                acc[i][j] = __builtin_amdgcn_mfma_f32_16x16x32_bf16(al4[i], bh4[j], acc[i][j], 0, 0, 0);
                acc[i][j] = __builtin_amdgcn_mfma_f32_16x16x32_bf16(ah4[i], bl4[j], acc[i][j], 0, 0, 0);
                acc[i][j] = __builtin_amdgcn_mfma_f32_16x16x32_bf16(ah4[i], bh4[j], acc[i][j], 0, 0, 0);
            }
    }

    // C/D layout: col = lane&15, row = quad*4 + reg
#pragma unroll
    for (int i = 0; i < 4; ++i) {
#pragma unroll
        for (int r = 0; r < 4; ++r) {
            int gm = m0 + wm * 64 + i * 16 + quad * 4 + r;
            if (MODE != 0 && gm >= rows) continue;
            long crow = (MODE != 0) ? ((long)rowoff + gm) : (long)gm;
#pragma unroll
            for (int j = 0; j < 4; ++j) {
                int col = n0 + wn * 64 + j * 16 + l15;
                float v = acc[i][j][r] + biasb[col];
                if constexpr (RELU) v = fmaxf(v, 0.f);
                if constexpr (SPLITOUT) {
                    unsigned short h, l;
                    split_bf(v, h, l);
                    Ch[crow * (long)N + col] = h;
                    Cl[crow * (long)N + col] = l;
                } else {
                    Cf[crow * (long)N + col] = v;
                }
            }
        }
    }
}

// ---------------------------------------------------------------------------
// fp32 SGEMM (embed GEMM K=200, batched pb@V)
// ---------------------------------------------------------------------------
__global__ __launch_bounds__(256)
void gemm_k(const float* __restrict__ A, const float* __restrict__ Bm,
            const float* __restrict__ bias, float* __restrict__ C,
            int K, int lda, int ldb, int ldc,
            long strA, long strB, long strC, int strBias)
{
    const int z  = blockIdx.z;
    const int m0 = blockIdx.y * 64, n0 = blockIdx.x * 64;
    const float* Ab    = A    + (long)z * strA;
    const float* Bb    = Bm   + (long)z * strB;
    const float* biasb = bias + (long)z * strBias;
    float*       Cb    = C    + (long)z * strC;

    __shared__ float As[16][68];
    __shared__ float Bs[16][64];

    const int tid = threadIdx.x;
    const int tx  = tid & 15, ty = tid >> 4;
    const int ar  = tid >> 2;
    const int akc = (tid & 3) * 4;
    const float* Arow = Ab + (long)(m0 + ar) * lda;
    const int bkr = tid >> 4;
    const int bnc = (tid & 15) * 4;

    float acc[4][4];
#pragma unroll
    for (int i = 0; i < 4; ++i)
#pragma unroll
        for (int j = 0; j < 4; ++j) acc[i][j] = 0.f;

    for (int k0 = 0; k0 < K; k0 += 16) {
        if (k0 + 16 <= K) {
            float4 a = *(const float4*)(Arow + k0 + akc);
            As[akc + 0][ar] = a.x; As[akc + 1][ar] = a.y;
            As[akc + 2][ar] = a.z; As[akc + 3][ar] = a.w;
        } else {
#pragma unroll
            for (int j = 0; j < 4; ++j) {
                int kk = k0 + akc + j;
                As[akc + j][ar] = (kk < K) ? Arow[kk] : 0.f;
            }
        }
        {
            int kk = k0 + bkr;
            float4 b;
            if (kk < K) b = *(const float4*)(Bb + (long)kk * ldb + n0 + bnc);
            else        b = make_float4(0.f, 0.f, 0.f, 0.f);
            *(float4*)&Bs[bkr][bnc] = b;
        }
        __syncthreads();
#pragma unroll
        for (int k = 0; k < 16; ++k) {
            float4 av = *(const float4*)&As[k][ty * 4];
            float4 bv = *(const float4*)&Bs[k][tx * 4];
            float am[4] = {av.x, av.y, av.z, av.w};
            float bn[4] = {bv.x, bv.y, bv.z, bv.w};
#pragma unroll
            for (int i = 0; i < 4; ++i)
#pragma unroll
                for (int j = 0; j < 4; ++j)
                    acc[i][j] = fmaf(am[i], bn[j], acc[i][j]);
        }
        __syncthreads();
    }
#pragma unroll
    for (int i = 0; i < 4; ++i) {
        float*       Cp = Cb + (long)(m0 + ty * 4 + i) * ldc + n0 + tx * 4;
        const float* bp = biasb + n0 + tx * 4;
#pragma unroll
        for (int j = 0; j < 4; ++j) Cp[j] = acc[i][j] + bp[j];
    }
}

// ---------------------------------------------------------------------------
// fp32 [R][C] -> split-bf16 [C][R] (hi, lo), batched over z
// ---------------------------------------------------------------------------
__global__ __launch_bounds__(256)
void transpose_split_k(const float* __restrict__ in,
                       unsigned short* __restrict__ oh, unsigned short* __restrict__ ol,
                       int R, int C, long strIn, long strOut)
{
    __shared__ float tile[32][33];
    const float* I = in + (long)blockIdx.z * strIn;
    unsigned short* OH = oh + (long)blockIdx.z * strOut;
    unsigned short* OL = ol + (long)blockIdx.z * strOut;
    int c0 = blockIdx.x * 32, r0 = blockIdx.y * 32;
    int tx = threadIdx.x & 31, ty = threadIdx.x >> 5;
#pragma unroll
    for (int i = 0; i < 4; ++i)
        tile[ty + i * 8][tx] = I[(long)(r0 + ty + i * 8) * C + c0 + tx];
    __syncthreads();
#pragma unroll
    for (int i = 0; i < 4; ++i) {
        unsigned short h, l;
        split_bf(tile[tx][ty + i * 8], h, l);
        long o = (long)(c0 + ty + i * 8) * R + r0 + tx;
        OH[o] = h; OL[o] = l;
    }
}

__global__ void cvt_split_k(const float* __restrict__ in,
                            unsigned short* __restrict__ oh,
                            unsigned short* __restrict__ ol, int n)
{
    int i = blockIdx.x * 256 + threadIdx.x;
    if (i < n) {
        unsigned short h, l;
        split_bf(in[i], h, l);
        oh[i] = h; ol[i] = l;
    }
}

__global__ void bias_cat_k(const float* __restrict__ a, const float* __restrict__ b,
                           float* __restrict__ o)
{
    int i = blockIdx.x * 256 + threadIdx.x;   // 1024
    o[i] = (i < D_) ? a[i] : b[i - D_];
}

// ---------------------------------------------------------------------------
__global__ void embed_gather_k(const int* __restrict__ src,
                               const float* __restrict__ table,
                               float* __restrict__ emb)
{
    int t = blockIdx.x;
    int v = src[t];
    for (int k = threadIdx.x; k < FEAT_; k += 256)
        emb[t * FEAT_ + k] = table[v * FEAT_ + k];
}

__global__ __launch_bounds__(256)
void pb_k(const float* __restrict__ frac, const float* __restrict__ pbW,
          const float* __restrict__ pbb, const float* __restrict__ pba,
          float* __restrict__ pb)
{
    int idx = blockIdx.x * 256 + threadIdx.x;
    int b = idx >> 14;
    int i = (idx >> 7) & 127;
    int j = idx & 127;
    float diff = (frac[b * T_ + j] - frac[b * T_ + i]) * 10.0f;
    float s = 0.f;
#pragma unroll
    for (int f = 0; f < NF_; ++f)
        s = fmaf(cosf(fmaf(diff, pbW[f], pbb[f])), pba[f], s);
    pb[idx] = s;
}

// kv[b,c] = sum_t K[b,t,c]*V[b,t,c]; K,V interleaved in KVb [BT][1024]
__global__ __launch_bounds__(256)
void kv_k(const float* __restrict__ KV, float* __restrict__ kv)
{
    int idx = blockIdx.x * 256 + threadIdx.x;
    int b = idx >> 9, c = idx & 511;
    const float* Kp = KV + (long)b * T_ * 1024 + c;
    float s = 0.f;
    for (int t = 0; t < T_; ++t) {
        const float* p = Kp + t * 1024;
        s = fmaf(p[0], p[D_], s);
    }
    kv[idx] = s;
}

// LayerNorm(x + add) -> out fp32 + split bf16
__global__ __launch_bounds__(256)
void ln_res_k(const float* __restrict__ x, const float* __restrict__ add,
              const float* __restrict__ g, const float* __restrict__ b,
              float* __restrict__ out, unsigned short* __restrict__ oh,
              unsigned short* __restrict__ ol)
{
    int wave = threadIdx.x >> 6, lane = threadIdx.x & 63;
    int row = blockIdx.x * 4 + wave;
    const float* xr = x   + (long)row * D_ + lane * 8;
    const float* ar = add + (long)row * D_ + lane * 8;
    float v[8]; float s = 0.f;
#pragma unroll
    for (int j = 0; j < 8; ++j) { v[j] = xr[j] + ar[j]; s += v[j]; }
#pragma unroll
    for (int off = 32; off > 0; off >>= 1) s += __shfl_xor(s, off, 64);
    float mean = s * (1.f / D_);
    float q = 0.f;
#pragma unroll
    for (int j = 0; j < 8; ++j) { float d = v[j] - mean; q += d * d; }
#pragma unroll
    for (int off = 32; off > 0; off >>= 1) q += __shfl_xor(q, off, 64);
    float inv = rsqrtf(q * (1.f / D_) + 1e-5f);
    float* orow = out + (long)row * D_ + lane * 8;
    unsigned short* hrow = oh + (long)row * D_ + lane * 8;
    unsigned short* lrow = ol + (long)row * D_ + lane * 8;
#pragma unroll
    for (int j = 0; j < 8; ++j) {
        int c = lane * 8 + j;
        float o = (v[j] - mean) * inv * g[c] + b[c];
        orow[j] = o;
        unsigned short hh, ll;
        split_bf(o, hh, ll);
        hrow[j] = hh; lrow[j] = ll;
    }
}

// LayerNorm(x + w0*eo0 + w1*eo1) -> out fp32 + split bf16
__global__ __launch_bounds__(256)
void ln_moe_k(const float* __restrict__ x, const float* __restrict__ eo,
              const int* __restrict__ tok_slot, const float* __restrict__ tok_w,
              const int* __restrict__ offsets,
              const float* __restrict__ g, const float* __restrict__ b,
              float* __restrict__ out, unsigned short* __restrict__ oh,
              unsigned short* __restrict__ ol)
{
    int wave = threadIdx.x >> 6, lane = threadIdx.x & 63;
    int row = blockIdx.x * 4 + wave;
    int  c0 = tok_slot[row * 2], c1 = tok_slot[row * 2 + 1];
    float w0 = tok_w[row * 2],  w1 = tok_w[row * 2 + 1];
    long r0 = offsets[c0 >> 12] + (c0 & 4095);
    long r1 = offsets[c1 >> 12] + (c1 & 4095);
    const float* xr = x  + (long)row * D_ + lane * 8;
    const float* e0 = eo + r0 * D_ + lane * 8;
    const float* e1 = eo + r1 * D_ + lane * 8;
    float v[8]; float s = 0.f;
#pragma unroll
    for (int j = 0; j < 8; ++j) {
        v[j] = xr[j] + w0 * e0[j] + w1 * e1[j];
        s += v[j];
    }
#pragma unroll
    for (int off = 32; off > 0; off >>= 1) s += __shfl_xor(s, off, 64);
    float mean = s * (1.f / D_);
    float q = 0.f;
#pragma unroll
    for (int j = 0; j < 8; ++j) { float d = v[j] - mean; q += d * d; }
#pragma unroll
    for (int off = 32; off > 0; off >>= 1) q += __shfl_xor(q, off, 64);
    float inv = rsqrtf(q * (1.f / D_) + 1e-5f);
    float* orow = out + (long)row * D_ + lane * 8;
    unsigned short* hrow = oh + (long)row * D_ + lane * 8;
    unsigned short* lrow = ol + (long)row * D_ + lane * 8;
#pragma unroll
    for (int j = 0; j < 8; ++j) {
        int c = lane * 8 + j;
        float o = (v[j] - mean) * inv * g[c] + b[c];
        orow[j] = o;
        unsigned short hh, ll;
        split_bf(o, hh, ll);
        hrow[j] = hh; lrow[j] = ll;
    }
}

__global__ __launch_bounds__(256)
void gate_k(const float* __restrict__ x, const float* __restrict__ gW,
            const float* __restrict__ gb, int* __restrict__ counts,
            int* __restrict__ tok_list, int* __restrict__ tok_slot,
            float* __restrict__ tok_w)
{
    int wave = threadIdx.x >> 6, lane = threadIdx.x & 63;
    int t = blockIdx.x * 4 + wave;
    float acc[8];
#pragma unroll
    for (int e = 0; e < 8; ++e) acc[e] = 0.f;
    const float* xr = x + (long)t * D_;
#pragma unroll
    for (int j = 0; j < 8; ++j) {
        int d = lane * 8 + j;
        float xv = xr[d];
        const float* w = gW + d * 8;
#pragma unroll
        for (int e = 0; e < 8; ++e) acc[e] = fmaf(xv, w[e], acc[e]);
    }
#pragma unroll
    for (int off = 32; off > 0; off >>= 1)
#pragma unroll
        for (int e = 0; e < 8; ++e) acc[e] += __shfl_xor(acc[e], off, 64);

    if (lane == 0) {
        float m = -1e30f;
#pragma unroll
        for (int e = 0; e < 8; ++e) { acc[e] += gb[e]; m = fmaxf(m, acc[e]); }
        float p[8]; float s = 0.f;
#pragma unroll
        for (int e = 0; e < 8; ++e) { p[e] = expf(acc[e] - m); s += p[e]; }
        float inv = 1.f / s;
        int e1 = 0;
        for (int e = 1; e < 8; ++e) if (p[e] > p[e1]) e1 = e;
        int e2 = -1;
        for (int e = 0; e < 8; ++e) {
            if (e == e1) continue;
            if (e2 < 0 || p[e] > p[e2]) e2 = e;
        }
        int s1 = atomicAdd(&counts[e1], 1);
        tok_list[e1 * BT_ + s1] = t;
        tok_slot[t * 2]     = (e1 << 12) | s1;
        tok_w[t * 2]        = p[e1] * inv;
        int s2 = atomicAdd(&counts[e2], 1);
        tok_list[e2 * BT_ + s2] = t;
        tok_slot[t * 2 + 1] = (e2 << 12) | s2;
        tok_w[t * 2 + 1]    = p[e2] * inv;
    }
}

__global__ void zero_counts_k(int* __restrict__ counts)
{
    if (threadIdx.x < E_) counts[threadIdx.x] = 0;
}

__global__ void scan_k(const int* __restrict__ counts, int* __restrict__ offsets)
{
    if (threadIdx.x == 0) {
        int s = 0;
        for (int e = 0; e < E_; ++e) { offsets[e] = s; s += counts[e]; }
    }
}

// ---------------------------------------------------------------------------
extern "C" void kernel_launch(void* const* d_in, const int* in_sizes, int n_in,
                              void* d_out, int out_size, void* d_ws, size_t ws_size,
                              hipStream_t stream)
{
    const int*   src   = (const int*)  d_in[0];
    const float* frac  = (const float*)d_in[1];
    const float* table = (const float*)d_in[2];
    const float* W_m2v = (const float*)d_in[3];
    const float* b_m2v = (const float*)d_in[4];
    const float* pbW   = (const float*)d_in[5];
    const float* pbb   = (const float*)d_in[6];
    const float* pba   = (const float*)d_in[7];
    const float* Wk    = (const float*)d_in[8];
    const float* bk    = (const float*)d_in[9];
    const float* Wv    = (const float*)d_in[10];
    const float* bv    = (const float*)d_in[11];
    const float* Wo    = (const float*)d_in[12];
    const float* bo    = (const float*)d_in[13];
    const float* ln1g  = (const float*)d_in[14];
    const float* ln1b  = (const float*)d_in[15];
    const float* ln2g  = (const float*)d_in[16];
    const float* ln2b  = (const float*)d_in[17];
    const float* gW    = (const float*)d_in[18];
    const float* gb    = (const float*)d_in[19];
    const float* eW1   = (const float*)d_in[20];
    const float* eb1   = (const float*)d_in[21];
    const float* eW2   = (const float*)d_in[22];
    const float* eb2   = (const float*)d_in[23];

    // ---- workspace layout (persistent) ----
    float* ws   = (float*)d_ws;
    float* x    = ws;  ws += (long)BT_ * D_;
    float* pb   = ws;  ws += (long)B_ * T_ * T_;
    float* eo   = ws;  ws += (long)2 * BT_ * D_;
    float* kv   = ws;  ws += B_ * D_;
    float* tokw = ws;  ws += 2 * BT_;
    float* kvbias = ws; ws += 2 * D_;
    unsigned short* us = (unsigned short*)ws;
    unsigned short* x_h   = us;  us += (long)BT_ * D_;
    unsigned short* x_l   = us;  us += (long)BT_ * D_;
    unsigned short* Wkv_h = us;  us += (long)2 * D_ * D_;   // [Wk^T ; Wv^T]
    unsigned short* Wkv_l = us;  us += (long)2 * D_ * D_;
    unsigned short* Wo_h  = us;  us += (long)D_ * D_;
    unsigned short* Wo_l  = us;  us += (long)D_ * D_;
    unsigned short* e1_h  = us;  us += (long)E_ * FF_ * D_;
    unsigned short* e1_l  = us;  us += (long)E_ * FF_ * D_;
    unsigned short* e2_h  = us;  us += (long)E_ * D_ * FF_;
    unsigned short* e2_l  = us;  us += (long)E_ * D_ * FF_;
    int* counts  = (int*)us;
    int* offsets = counts + 8;
    int* toklist = offsets + 8;
    int* tokslot = toklist + E_ * BT_;
    // ---- aliased region: {emb, KVb, wv, tmp, wv pair} vs {h pair} ----
    char* ar = (char*)(tokslot + 2 * BT_);
    ar = (char*)(((size_t)ar + 255) & ~(size_t)255);
    unsigned short* h_h = (unsigned short*)ar;               // [2*BT][FF]
    unsigned short* h_l = h_h + (long)2 * BT_ * FF_;
    float* emb  = (float*)ar;
    float* KVb  = emb + (long)BT_ * FEAT_;                   // [BT][1024]
    float* wv   = KVb + (long)BT_ * 2 * D_;
    float* tmp  = wv  + (long)BT_ * D_;
    unsigned short* wv_h = (unsigned short*)(tmp + (long)BT_ * D_);
    unsigned short* wv_l = wv_h + (long)BT_ * D_;

    // ---- embedder (fp32) ----
    embed_gather_k<<<BT_, 256, 0, stream>>>(src, table, emb);
    gemm_k<<<dim3(8, 64, 1), 256, 0, stream>>>(
        emb, W_m2v, b_m2v, x, FEAT_, FEAT_, D_, D_, 0, 0, 0, 0);
    cvt_split_k<<<(BT_ * D_) / 256, 256, 0, stream>>>(x, x_h, x_l, BT_ * D_);

    // ---- fourier positional bias ----
    pb_k<<<(B_ * T_ * T_) / 256, 256, 0, stream>>>(frac, pbW, pbb, pba, pb);

    for (int i = 0; i < NL_; ++i) {
        // weight transposes: fp32 [K][N] -> split bf16 [N][K]
        transpose_split_k<<<dim3(16, 16, 1), 256, 0, stream>>>(
            Wk + (long)i * D_ * D_, Wkv_h, Wkv_l, D_, D_, 0, 0);
        transpose_split_k<<<dim3(16, 16, 1), 256, 0, stream>>>(
            Wv + (long)i * D_ * D_, Wkv_h + (long)D_ * D_, Wkv_l + (long)D_ * D_,
            D_, D_, 0, 0);
        transpose_split_k<<<dim3(16, 16, 1), 256, 0, stream>>>(
            Wo + (long)i * D_ * D_, Wo_h, Wo_l, D_, D_, 0, 0);
        transpose_split_k<<<dim3(64, 16, E_), 256, 0, stream>>>(
            eW1 + (long)i * E_ * D_ * FF_, e1_h, e1_l, D_, FF_,
            (long)D_ * FF_, (long)FF_ * D_);
        transpose_split_k<<<dim3(16, 64, E_), 256, 0, stream>>>(
            eW2 + (long)i * E_ * FF_ * D_, e2_h, e2_l, FF_, D_,
            (long)FF_ * D_, (long)D_ * FF_);
        bias_cat_k<<<4, 256, 0, stream>>>(bk + i * D_, bv + i * D_, kvbias);

        // merged K|V projection: [BT][1024] = x @ [Wk Wv]
        mgemm_k<0, false, false><<<dim3(8, 32, 1), 256, 0, stream>>>(
            x_h, x_l, Wkv_h, Wkv_l, kvbias,
            KVb, nullptr, nullptr, BT_, D_, 2 * D_, 0, 0,
            nullptr, nullptr, nullptr);

        kv_k<<<(B_ * D_) / 256, 256, 0, stream>>>(KVb, kv);

        // wv[b] = pb[b] @ V[b] + kv[b]  (fp32; V = KVb cols 512..1023)
        gemm_k<<<dim3(8, 2, B_), 256, 0, stream>>>(
            pb, KVb + D_, kv, wv, T_, T_, 2 * D_, D_,
            (long)T_ * T_, (long)T_ * 2 * D_, (long)T_ * D_, D_);
        cvt_split_k<<<(BT_ * D_) / 256, 256, 0, stream>>>(wv, wv_h, wv_l, BT_ * D_);

        // attention output projection
        mgemm_k<0, false, false><<<dim3(4, 32, 1), 256, 0, stream>>>(
            wv_h, wv_l, Wo_h, Wo_l, bo + i * D_,
            tmp, nullptr, nullptr, BT_, D_, D_, 0, 0, nullptr, nullptr, nullptr);

        // x = LN1(x + tmp)
        ln_res_k<<<BT_ / 4, 256, 0, stream>>>(x, tmp, ln1g + i * D_, ln1b + i * D_,
                                              x, x_h, x_l);

        // gating + routing
        zero_counts_k<<<1, 64, 0, stream>>>(counts);
        gate_k<<<BT_ / 4, 256, 0, stream>>>(x, gW + (long)i * D_ * E_, gb + i * E_,
                                            counts, toklist, tokslot, tokw);
        scan_k<<<1, 1, 0, stream>>>(counts, offsets);

        // MoE expert GEMMs (split MFMA)
        mgemm_k<1, true, true><<<dim3(16, 32, E_), 256, 0, stream>>>(
            x_h, x_l, e1_h, e1_l, eb1 + (long)i * E_ * FF_,
            nullptr, h_h, h_l, 0, D_, FF_,
            (long)FF_ * D_, FF_, counts, offsets, toklist);
        mgemm_k<2, false, false><<<dim3(4, 32, E_), 256, 0, stream>>>(
            h_h, h_l, e2_h, e2_l, eb2 + (long)i * E_ * D_,
            eo, nullptr, nullptr, 0, FF_, D_,
            (long)D_ * FF_, D_, counts, offsets, toklist);

        // x = LN2(x + w0*eo0 + w1*eo1)
        float* dst = (i == NL_ - 1) ? (float*)d_out : x;
        ln_moe_k<<<BT_ / 4, 256, 0, stream>>>(x, eo, tokslot, tokw, offsets,
                                              ln2g + i * D_, ln2b + i * D_,
                                              dst, x_h, x_l);
    }
}

// Round 6
// 1355.130 us; speedup vs baseline: 2.1317x; 1.0905x over previous
//
#include <hip/hip_runtime.h>
#include <math.h>

#define B_    32
#define T_    128
#define D_    512
#define FF_   2048
#define E_    8
#define NL_   3
#define NF_   16
#define FEAT_ 200
#define BT_   4096   // B*T

typedef short bf16x8 __attribute__((ext_vector_type(8)));
typedef float f32x4  __attribute__((ext_vector_type(4)));

__device__ inline unsigned short f2bf(float f) {
    unsigned u = __float_as_uint(f);
    unsigned r = (u + 0x7fffu + ((u >> 16) & 1u)) >> 16;   // RNE
    return (unsigned short)r;
}
// f = hi + lo + eps, |eps| <= 2^-18 |f|
__device__ inline void split_bf(float f, unsigned short& h, unsigned short& l) {
    h = f2bf(f);
    float fh = __uint_as_float(((unsigned)h) << 16);
    l = f2bf(f - fh);
}

// async HBM->LDS DMA, 16B/lane, no VGPR round-trip. LDS dest is
// wave-uniform base + lane*16 (HW rule).
__device__ __forceinline__ void ld_g2l(const unsigned short* g, unsigned short* l)
{
    __builtin_amdgcn_global_load_lds(
        (const __attribute__((address_space(1))) unsigned int*)(uintptr_t)g,
        (__attribute__((address_space(3))) unsigned int*)(uintptr_t)l,
        16, 0, 0);
}

// ---------------------------------------------------------------------------
// Split-bf16 MFMA GEMM, DMA-staged + ping-pong LDS double buffer (m97 style).
// C = A @ Bt^T + bias, fp32-equivalent precision (3-term MFMA).
// A as (Ah, Al) bf16 [M][K]; Bt as (Bh, Bl) [N][K] (K-contig).
// Tile 128x128, BK=32, 4 waves (2x2), each 64x64 via 4x4 of 16x16x32 MFMA.
// LDS: per buffer, 4 arrays (Ah,Al,Bh,Bl) of 128 rows x 32 shorts; within a
// row, global 16B-seg s lands at pos p = s ^ ((r>>1)&3) -> frag ds_read_b128
// is 2-way bank aliased (free).
// MODE 0: direct rows. MODE 1: A rows via tok_list[z], C rows offsets[z]+m.
// MODE 2: A and C rows at offsets[z]+m.
// ---------------------------------------------------------------------------
template <int MODE, bool SPLITOUT, bool RELU>
__global__ __launch_bounds__(256)
void mgemm_k(const unsigned short* __restrict__ Ah, const unsigned short* __restrict__ Al,
             const unsigned short* __restrict__ Bh, const unsigned short* __restrict__ Bl,
             const float* __restrict__ bias,
             float* __restrict__ Cf, unsigned short* __restrict__ Ch,
             unsigned short* __restrict__ Cl,
             int M, int K, int N, long strB, int strBias,
             const int* __restrict__ counts, const int* __restrict__ offsets,
             const int* __restrict__ tok_list)
{
    const int z  = blockIdx.z;
    const int m0 = blockIdx.y * 128, n0 = blockIdx.x * 128;
    int rows, rowoff = 0;
    if constexpr (MODE != 0) {
        rows = counts[z];
        if (m0 >= rows) return;
        rowoff = offsets[z];
    } else {
        rows = M;
    }
    const unsigned short* Bhb = Bh + (long)z * strB;
    const unsigned short* Blb = Bl + (long)z * strB;
    const float* biasb = bias + (long)z * strBias;

    // 2 buffers x 4 arrays x 4096 shorts (8 KB) = 64 KB
    __shared__ unsigned short S[2][4 * 4096];

    const int tid  = threadIdx.x;
    const int w    = tid >> 6, lane = tid & 63;
    const int wm = w & 1, wn = w >> 1;
    const int l15 = lane & 15, quad = lane >> 4;

    // staging map: wave w, issue j covers tile rows r = w*32 + (lane>>2) (+16*j)
    // LDS pos p = lane&3, global seg s = p ^ ((r>>1)&3) = p ^ ((lane>>3)&3)
    const int lrow0 = w * 32 + (lane >> 2);
    const int lrow1 = lrow0 + 16;
    const int sseg  = (lane & 3) ^ ((lane >> 3) & 3);
    const int lb0   = (w * 2 + 0) * 512;             // uniform short-offset in array
    const int lb1   = (w * 2 + 1) * 512;

    long ga0, ga1;
    if constexpr (MODE == 1) {
        int m_a = m0 + lrow0; if (m_a >= rows) m_a = rows - 1;
        int m_b = m0 + lrow1; if (m_b >= rows) m_b = rows - 1;
        ga0 = tok_list[z * BT_ + m_a];
        ga1 = tok_list[z * BT_ + m_b];
    } else if constexpr (MODE == 2) {
        int m_a = m0 + lrow0; if (m_a >= rows) m_a = rows - 1;
        int m_b = m0 + lrow1; if (m_b >= rows) m_b = rows - 1;
        ga0 = (long)rowoff + m_a;
        ga1 = (long)rowoff + m_b;
    } else {
        ga0 = m0 + lrow0;
        ga1 = m0 + lrow1;
    }
    const long aoff0 = ga0 * (long)K + sseg * 8;
    const long aoff1 = ga1 * (long)K + sseg * 8;
    const long boff0 = (long)(n0 + lrow0) * K + sseg * 8;
    const long boff1 = (long)(n0 + lrow1) * K + sseg * 8;

    f32x4 acc[4][4];
#pragma unroll
    for (int i = 0; i < 4; ++i)
#pragma unroll
        for (int j = 0; j < 4; ++j) acc[i][j] = (f32x4)0.f;

    const int xq = quad ^ ((l15 >> 1) & 3);          // swizzled read pos

    // ---- prologue: DMA tile 0 into buffer 0 ----
    {
        unsigned short* Sb = S[0];
        ld_g2l(Ah  + aoff0, Sb + 0 * 4096 + lb0);
        ld_g2l(Ah  + aoff1, Sb + 0 * 4096 + lb1);
        ld_g2l(Al  + aoff0, Sb + 1 * 4096 + lb0);
        ld_g2l(Al  + aoff1, Sb + 1 * 4096 + lb1);
        ld_g2l(Bhb + boff0, Sb + 2 * 4096 + lb0);
        ld_g2l(Bhb + boff1, Sb + 2 * 4096 + lb1);
        ld_g2l(Blb + boff0, Sb + 3 * 4096 + lb0);
        ld_g2l(Blb + boff1, Sb + 3 * 4096 + lb1);
    }

    unsigned short* Scur = S[0];
    unsigned short* Snxt = S[1];

    for (int k0 = 0; k0 < K; k0 += 32) {
        __syncthreads();        // drains DMA for tile k0 (in flight one full iter)

        if (k0 + 32 < K) {      // prefetch tile k0+32 into the other buffer
            int kn = k0 + 32;
            ld_g2l(Ah  + aoff0 + kn, Snxt + 0 * 4096 + lb0);
            ld_g2l(Ah  + aoff1 + kn, Snxt + 0 * 4096 + lb1);
            ld_g2l(Al  + aoff0 + kn, Snxt + 1 * 4096 + lb0);
            ld_g2l(Al  + aoff1 + kn, Snxt + 1 * 4096 + lb1);
            ld_g2l(Bhb + boff0 + kn, Snxt + 2 * 4096 + lb0);
            ld_g2l(Bhb + boff1 + kn, Snxt + 2 * 4096 + lb1);
            ld_g2l(Blb + boff0 + kn, Snxt + 3 * 4096 + lb0);
            ld_g2l(Blb + boff1 + kn, Snxt + 3 * 4096 + lb1);
        }

        bf16x8 ah4[4], al4[4], bh4[4], bl4[4];
#pragma unroll
        for (int i = 0; i < 4; ++i) {
            int ro = (wm * 64 + i * 16 + l15) * 32 + xq * 8;
            ah4[i] = *(const bf16x8*)&Scur[0 * 4096 + ro];
            al4[i] = *(const bf16x8*)&Scur[1 * 4096 + ro];
        }
#pragma unroll
        for (int j = 0; j < 4; ++j) {
            int ro = (wn * 64 + j * 16 + l15) * 32 + xq * 8;
            bh4[j] = *(const bf16x8*)&Scur[2 * 4096 + ro];
            bl4[j] = *(const bf16x8*)&Scur[3 * 4096 + ro];
        }
#pragma unroll
        for (int i = 0; i < 4; ++i)
#pragma unroll
            for (int j = 0; j < 4; ++j) {
                acc[i][j] = __builtin_amdgcn_mfma_f32_16x16x32_bf16(al4[i], bh4[j], acc[i][j], 0, 0, 0);
                acc[i][j] = __builtin_amdgcn_mfma_f32_16x16x32_bf16(ah4[i], bl4[j], acc[i][j], 0, 0, 0);
                acc[i][j] = __builtin_amdgcn_mfma_f32_16x16x32_bf16(ah4[i], bh4[j], acc[i][j], 0, 0, 0);
            }

        unsigned short* t = Scur; Scur = Snxt; Snxt = t;
    }

    // C/D layout: col = lane&15, row = quad*4 + reg
#pragma unroll
    for (int i = 0; i < 4; ++i) {
#pragma unroll
        for (int r = 0; r < 4; ++r) {
            int gm = m0 + wm * 64 + i * 16 + quad * 4 + r;
            if (MODE != 0 && gm >= rows) continue;
            long crow = (MODE != 0) ? ((long)rowoff + gm) : (long)gm;
#pragma unroll
            for (int j = 0; j < 4; ++j) {
                int col = n0 + wn * 64 + j * 16 + l15;
                float v = acc[i][j][r] + biasb[col];
                if constexpr (RELU) v = fmaxf(v, 0.f);
                if constexpr (SPLITOUT) {
                    unsigned short h, l;
                    split_bf(v, h, l);
                    Ch[crow * (long)N + col] = h;
                    Cl[crow * (long)N + col] = l;
                } else {
                    Cf[crow * (long)N + col] = v;
                }
            }
        }
    }
}

// ---------------------------------------------------------------------------
// fp32 SGEMM (embed GEMM K=200, batched pb@V). Optional fused split-bf16 out.
// ---------------------------------------------------------------------------
template <bool WF32, bool SPLIT>
__global__ __launch_bounds__(256)
void gemm_k(const float* __restrict__ A, const float* __restrict__ Bm,
            const float* __restrict__ bias, float* __restrict__ C,
            unsigned short* __restrict__ Oh, unsigned short* __restrict__ Ol,
            int K, int lda, int ldb, int ldc,
            long strA, long strB, long strC, int strBias)
{
    const int z  = blockIdx.z;
    const int m0 = blockIdx.y * 64, n0 = blockIdx.x * 64;
    const float* Ab    = A    + (long)z * strA;
    const float* Bb    = Bm   + (long)z * strB;
    const float* biasb = bias + (long)z * strBias;

    __shared__ float As[16][68];
    __shared__ float Bs[16][64];

    const int tid = threadIdx.x;
    const int tx  = tid & 15, ty = tid >> 4;
    const int ar  = tid >> 2;
    const int akc = (tid & 3) * 4;
    const float* Arow = Ab + (long)(m0 + ar) * lda;
    const int bkr = tid >> 4;
    const int bnc = (tid & 15) * 4;

    float acc[4][4];
#pragma unroll
    for (int i = 0; i < 4; ++i)
#pragma unroll
        for (int j = 0; j < 4; ++j) acc[i][j] = 0.f;

    for (int k0 = 0; k0 < K; k0 += 16) {
        if (k0 + 16 <= K) {
            float4 a = *(const float4*)(Arow + k0 + akc);
            As[akc + 0][ar] = a.x; As[akc + 1][ar] = a.y;
            As[akc + 2][ar] = a.z; As[akc + 3][ar] = a.w;
        } else {
#pragma unroll
            for (int j = 0; j < 4; ++j) {
                int kk = k0 + akc + j;
                As[akc + j][ar] = (kk < K) ? Arow[kk] : 0.f;
            }
        }
        {
            int kk = k0 + bkr;
            float4 b;
            if (kk < K) b = *(const float4*)(Bb + (long)kk * ldb + n0 + bnc);
            else        b = make_float4(0.f, 0.f, 0.f, 0.f);
            *(float4*)&Bs[bkr][bnc] = b;
        }
        __syncthreads();
#pragma unroll
        for (int k = 0; k < 16; ++k) {
            float4 av = *(const float4*)&As[k][ty * 4];
            float4 bv = *(const float4*)&Bs[k][tx * 4];
            float am[4] = {av.x, av.y, av.z, av.w};
            float bn[4] = {bv.x, bv.y, bv.z, bv.w};
#pragma unroll
            for (int i = 0; i < 4; ++i)
#pragma unroll
                for (int j = 0; j < 4; ++j)
                    acc[i][j] = fmaf(am[i], bn[j], acc[i][j]);
        }
        __syncthreads();
    }
#pragma unroll
    for (int i = 0; i < 4; ++i) {
        long row = (long)z * (strC / 1) + 0;   // placeholder (unused)
        (void)row;
        long base = ((long)z * strC) + (long)(m0 + ty * 4 + i) * ldc + n0 + tx * 4;
        const float* bp = biasb + n0 + tx * 4;
#pragma unroll
        for (int j = 0; j < 4; ++j) {
            float v = acc[i][j] + bp[j];
            if constexpr (WF32) C[base + j] = v;
            if constexpr (SPLIT) {
                unsigned short h, l;
                split_bf(v, h, l);
                Oh[base + j] = h;
                Ol[base + j] = l;
            }
        }
    }
}

// ---------------------------------------------------------------------------
// fp32 [R][C] -> split-bf16 [C][R] (hi, lo), batched over z
// ---------------------------------------------------------------------------
__global__ __launch_bounds__(256)
void transpose_split_k(const float* __restrict__ in,
                       unsigned short* __restrict__ oh, unsigned short* __restrict__ ol,
                       int R, int C, long strIn, long strOut)
{
    __shared__ float tile[32][33];
    const float* I = in + (long)blockIdx.z * strIn;
    unsigned short* OH = oh + (long)blockIdx.z * strOut;
    unsigned short* OL = ol + (long)blockIdx.z * strOut;
    int c0 = blockIdx.x * 32, r0 = blockIdx.y * 32;
    int tx = threadIdx.x & 31, ty = threadIdx.x >> 5;
#pragma unroll
    for (int i = 0; i < 4; ++i)
        tile[ty + i * 8][tx] = I[(long)(r0 + ty + i * 8) * C + c0 + tx];
    __syncthreads();
#pragma unroll
    for (int i = 0; i < 4; ++i) {
        unsigned short h, l;
        split_bf(tile[tx][ty + i * 8], h, l);
        long o = (long)(c0 + ty + i * 8) * R + r0 + tx;
        OH[o] = h; OL[o] = l;
    }
}

__global__ void bias_cat_k(const float* __restrict__ a, const float* __restrict__ b,
                           float* __restrict__ o)
{
    int i = blockIdx.x * 256 + threadIdx.x;   // 1024
    o[i] = (i < D_) ? a[i] : b[i - D_];
}

// ---------------------------------------------------------------------------
__global__ void embed_gather_k(const int* __restrict__ src,
                               const float* __restrict__ table,
                               float* __restrict__ emb)
{
    int t = blockIdx.x;
    int v = src[t];
    for (int k = threadIdx.x; k < FEAT_; k += 256)
        emb[t * FEAT_ + k] = table[v * FEAT_ + k];
}

__global__ __launch_bounds__(256)
void pb_k(const float* __restrict__ frac, const float* __restrict__ pbW,
          const float* __restrict__ pbb, const float* __restrict__ pba,
          float* __restrict__ pb)
{
    int idx = blockIdx.x * 256 + threadIdx.x;
    int b = idx >> 14;
    int i = (idx >> 7) & 127;
    int j = idx & 127;
    float diff = (frac[b * T_ + j] - frac[b * T_ + i]) * 10.0f;
    float s = 0.f;
#pragma unroll
    for (int f = 0; f < NF_; ++f)
        s = fmaf(cosf(fmaf(diff, pbW[f], pbb[f])), pba[f], s);
    pb[idx] = s;
}

// kv[b,c] = sum_t K[b,t,c]*V[b,t,c]; K,V interleaved in KVb [BT][1024]
__global__ __launch_bounds__(256)
void kv_k(const float* __restrict__ KV, float* __restrict__ kv)
{
    int idx = blockIdx.x * 256 + threadIdx.x;
    int b = idx >> 9, c = idx & 511;
    const float* Kp = KV + (long)b * T_ * 1024 + c;
    float s = 0.f;
    for (int t = 0; t < T_; ++t) {
        const float* p = Kp + t * 1024;
        s = fmaf(p[0], p[D_], s);
    }
    kv[idx] = s;
}

// LayerNorm(x + add) -> out fp32 + split bf16
__global__ __launch_bounds__(256)
void ln_res_k(const float* __restrict__ x, const float* __restrict__ add,
              const float* __restrict__ g, const float* __restrict__ b,
              float* __restrict__ out, unsigned short* __restrict__ oh,
              unsigned short* __restrict__ ol)
{
    int wave = threadIdx.x >> 6, lane = threadIdx.x & 63;
    int row = blockIdx.x * 4 + wave;
    const float* xr = x   + (long)row * D_ + lane * 8;
    const float* ar = add + (long)row * D_ + lane * 8;
    float v[8]; float s = 0.f;
#pragma unroll
    for (int j = 0; j < 8; ++j) { v[j] = xr[j] + ar[j]; s += v[j]; }
#pragma unroll
    for (int off = 32; off > 0; off >>= 1) s += __shfl_xor(s, off, 64);
    float mean = s * (1.f / D_);
    float q = 0.f;
#pragma unroll
    for (int j = 0; j < 8; ++j) { float d = v[j] - mean; q += d * d; }
#pragma unroll
    for (int off = 32; off > 0; off >>= 1) q += __shfl_xor(q, off, 64);
    float inv = rsqrtf(q * (1.f / D_) + 1e-5f);
    float* orow = out + (long)row * D_ + lane * 8;
    unsigned short* hrow = oh + (long)row * D_ + lane * 8;
    unsigned short* lrow = ol + (long)row * D_ + lane * 8;
#pragma unroll
    for (int j = 0; j < 8; ++j) {
        int c = lane * 8 + j;
        float o = (v[j] - mean) * inv * g[c] + b[c];
        orow[j] = o;
        unsigned short hh, ll;
        split_bf(o, hh, ll);
        hrow[j] = hh; lrow[j] = ll;
    }
}

// LayerNorm(x + w0*eo0 + w1*eo1) -> out fp32 + split bf16
__global__ __launch_bounds__(256)
void ln_moe_k(const float* __restrict__ x, const float* __restrict__ eo,
              const int* __restrict__ tok_slot, const float* __restrict__ tok_w,
              const int* __restrict__ offsets,
              const float* __restrict__ g, const float* __restrict__ b,
              float* __restrict__ out, unsigned short* __restrict__ oh,
              unsigned short* __restrict__ ol)
{
    int wave = threadIdx.x >> 6, lane = threadIdx.x & 63;
    int row = blockIdx.x * 4 + wave;
    int  c0 = tok_slot[row * 2], c1 = tok_slot[row * 2 + 1];
    float w0 = tok_w[row * 2],  w1 = tok_w[row * 2 + 1];
    long r0 = offsets[c0 >> 12] + (c0 & 4095);
    long r1 = offsets[c1 >> 12] + (c1 & 4095);
    const float* xr = x  + (long)row * D_ + lane * 8;
    const float* e0 = eo + r0 * D_ + lane * 8;
    const float* e1 = eo + r1 * D_ + lane * 8;
    float v[8]; float s = 0.f;
#pragma unroll
    for (int j = 0; j < 8; ++j) {
        v[j] = xr[j] + w0 * e0[j] + w1 * e1[j];
        s += v[j];
    }
#pragma unroll
    for (int off = 32; off > 0; off >>= 1) s += __shfl_xor(s, off, 64);
    float mean = s * (1.f / D_);
    float q = 0.f;
#pragma unroll
    for (int j = 0; j < 8; ++j) { float d = v[j] - mean; q += d * d; }
#pragma unroll
    for (int off = 32; off > 0; off >>= 1) q += __shfl_xor(q, off, 64);
    float inv = rsqrtf(q * (1.f / D_) + 1e-5f);
    float* orow = out + (long)row * D_ + lane * 8;
    unsigned short* hrow = oh + (long)row * D_ + lane * 8;
    unsigned short* lrow = ol + (long)row * D_ + lane * 8;
#pragma unroll
    for (int j = 0; j < 8; ++j) {
        int c = lane * 8 + j;
        float o = (v[j] - mean) * inv * g[c] + b[c];
        orow[j] = o;
        unsigned short hh, ll;
        split_bf(o, hh, ll);
        hrow[j] = hh; lrow[j] = ll;
    }
}

__global__ __launch_bounds__(256)
void gate_k(const float* __restrict__ x, const float* __restrict__ gW,
            const float* __restrict__ gb, int* __restrict__ counts,
            int* __restrict__ tok_list, int* __restrict__ tok_slot,
            float* __restrict__ tok_w)
{
    int wave = threadIdx.x >> 6, lane = threadIdx.x & 63;
    int t = blockIdx.x * 4 + wave;
    float acc[8];
#pragma unroll
    for (int e = 0; e < 8; ++e) acc[e] = 0.f;
    const float* xr = x + (long)t * D_;
#pragma unroll
    for (int j = 0; j < 8; ++j) {
        int d = lane * 8 + j;
        float xv = xr[d];
        const float* w = gW + d * 8;
#pragma unroll
        for (int e = 0; e < 8; ++e) acc[e] = fmaf(xv, w[e], acc[e]);
    }
#pragma unroll
    for (int off = 32; off > 0; off >>= 1)
#pragma unroll
        for (int e = 0; e < 8; ++e) acc[e] += __shfl_xor(acc[e], off, 64);

    if (lane == 0) {
        float m = -1e30f;
#pragma unroll
        for (int e = 0; e < 8; ++e) { acc[e] += gb[e]; m = fmaxf(m, acc[e]); }
        float p[8]; float s = 0.f;
#pragma unroll
        for (int e = 0; e < 8; ++e) { p[e] = expf(acc[e] - m); s += p[e]; }
        float inv = 1.f / s;
        int e1 = 0;
        for (int e = 1; e < 8; ++e) if (p[e] > p[e1]) e1 = e;
        int e2 = -1;
        for (int e = 0; e < 8; ++e) {
            if (e == e1) continue;
            if (e2 < 0 || p[e] > p[e2]) e2 = e;
        }
        int s1 = atomicAdd(&counts[e1], 1);
        tok_list[e1 * BT_ + s1] = t;
        tok_slot[t * 2]     = (e1 << 12) | s1;
        tok_w[t * 2]        = p[e1] * inv;
        int s2 = atomicAdd(&counts[e2], 1);
        tok_list[e2 * BT_ + s2] = t;
        tok_slot[t * 2 + 1] = (e2 << 12) | s2;
        tok_w[t * 2 + 1]    = p[e2] * inv;
    }
}

__global__ void zero_counts_k(int* __restrict__ counts)
{
    if (threadIdx.x < E_) counts[threadIdx.x] = 0;
}

__global__ void scan_k(const int* __restrict__ counts, int* __restrict__ offsets)
{
    if (threadIdx.x == 0) {
        int s = 0;
        for (int e = 0; e < E_; ++e) { offsets[e] = s; s += counts[e]; }
    }
}

// ---------------------------------------------------------------------------
extern "C" void kernel_launch(void* const* d_in, const int* in_sizes, int n_in,
                              void* d_out, int out_size, void* d_ws, size_t ws_size,
                              hipStream_t stream)
{
    const int*   src   = (const int*)  d_in[0];
    const float* frac  = (const float*)d_in[1];
    const float* table = (const float*)d_in[2];
    const float* W_m2v = (const float*)d_in[3];
    const float* b_m2v = (const float*)d_in[4];
    const float* pbW   = (const float*)d_in[5];
    const float* pbb   = (const float*)d_in[6];
    const float* pba   = (const float*)d_in[7];
    const float* Wk    = (const float*)d_in[8];
    const float* bk    = (const float*)d_in[9];
    const float* Wv    = (const float*)d_in[10];
    const float* bv    = (const float*)d_in[11];
    const float* Wo    = (const float*)d_in[12];
    const float* bo    = (const float*)d_in[13];
    const float* ln1g  = (const float*)d_in[14];
    const float* ln1b  = (const float*)d_in[15];
    const float* ln2g  = (const float*)d_in[16];
    const float* ln2b  = (const float*)d_in[17];
    const float* gW    = (const float*)d_in[18];
    const float* gb    = (const float*)d_in[19];
    const float* eW1   = (const float*)d_in[20];
    const float* eb1   = (const float*)d_in[21];
    const float* eW2   = (const float*)d_in[22];
    const float* eb2   = (const float*)d_in[23];

    // ---- workspace layout (persistent) ----
    float* ws   = (float*)d_ws;
    float* x    = ws;  ws += (long)BT_ * D_;
    float* pb   = ws;  ws += (long)B_ * T_ * T_;
    float* eo   = ws;  ws += (long)2 * BT_ * D_;
    float* kv   = ws;  ws += B_ * D_;
    float* tokw = ws;  ws += 2 * BT_;
    float* kvbias = ws; ws += 2 * D_;
    unsigned short* us = (unsigned short*)ws;
    unsigned short* x_h   = us;  us += (long)BT_ * D_;
    unsigned short* x_l   = us;  us += (long)BT_ * D_;
    unsigned short* Wkv_h = us;  us += (long)2 * D_ * D_;   // [Wk^T ; Wv^T]
    unsigned short* Wkv_l = us;  us += (long)2 * D_ * D_;
    unsigned short* Wo_h  = us;  us += (long)D_ * D_;
    unsigned short* Wo_l  = us;  us += (long)D_ * D_;
    unsigned short* e1_h  = us;  us += (long)E_ * FF_ * D_;
    unsigned short* e1_l  = us;  us += (long)E_ * FF_ * D_;
    unsigned short* e2_h  = us;  us += (long)E_ * D_ * FF_;
    unsigned short* e2_l  = us;  us += (long)E_ * D_ * FF_;
    int* counts  = (int*)us;
    int* offsets = counts + 8;
    int* toklist = offsets + 8;
    int* tokslot = toklist + E_ * BT_;
    // ---- aliased region: {emb, KVb, tmp, wv pair} vs {h pair} ----
    char* ar = (char*)(tokslot + 2 * BT_);
    ar = (char*)(((size_t)ar + 255) & ~(size_t)255);
    unsigned short* h_h = (unsigned short*)ar;               // [2*BT][FF]
    unsigned short* h_l = h_h + (long)2 * BT_ * FF_;
    float* emb  = (float*)ar;
    float* KVb  = emb + (long)BT_ * FEAT_;                   // [BT][1024]
    float* tmp  = KVb + (long)BT_ * 2 * D_;
    unsigned short* wv_h = (unsigned short*)(tmp + (long)BT_ * D_);
    unsigned short* wv_l = wv_h + (long)BT_ * D_;

    // ---- embedder (fp32, fused split epilogue) ----
    embed_gather_k<<<BT_, 256, 0, stream>>>(src, table, emb);
    gemm_k<true, true><<<dim3(8, 64, 1), 256, 0, stream>>>(
        emb, W_m2v, b_m2v, x, x_h, x_l, FEAT_, FEAT_, D_, D_, 0, 0, 0, 0);

    // ---- fourier positional bias ----
    pb_k<<<(B_ * T_ * T_) / 256, 256, 0, stream>>>(frac, pbW, pbb, pba, pb);

    for (int i = 0; i < NL_; ++i) {
        // weight transposes: fp32 [K][N] -> split bf16 [N][K]
        transpose_split_k<<<dim3(16, 16, 1), 256, 0, stream>>>(
            Wk + (long)i * D_ * D_, Wkv_h, Wkv_l, D_, D_, 0, 0);
        transpose_split_k<<<dim3(16, 16, 1), 256, 0, stream>>>(
            Wv + (long)i * D_ * D_, Wkv_h + (long)D_ * D_, Wkv_l + (long)D_ * D_,
            D_, D_, 0, 0);
        transpose_split_k<<<dim3(16, 16, 1), 256, 0, stream>>>(
            Wo + (long)i * D_ * D_, Wo_h, Wo_l, D_, D_, 0, 0);
        transpose_split_k<<<dim3(64, 16, E_), 256, 0, stream>>>(
            eW1 + (long)i * E_ * D_ * FF_, e1_h, e1_l, D_, FF_,
            (long)D_ * FF_, (long)FF_ * D_);
        transpose_split_k<<<dim3(16, 64, E_), 256, 0, stream>>>(
            eW2 + (long)i * E_ * FF_ * D_, e2_h, e2_l, FF_, D_,
            (long)FF_ * D_, (long)D_ * FF_);
        bias_cat_k<<<4, 256, 0, stream>>>(bk + i * D_, bv + i * D_, kvbias);

        // merged K|V projection: [BT][1024] = x @ [Wk Wv]
        mgemm_k<0, false, false><<<dim3(8, 32, 1), 256, 0, stream>>>(
            x_h, x_l, Wkv_h, Wkv_l, kvbias,
            KVb, nullptr, nullptr, BT_, D_, 2 * D_, 0, 0,
            nullptr, nullptr, nullptr);

        kv_k<<<(B_ * D_) / 256, 256, 0, stream>>>(KVb, kv);

        // wv[b] = pb[b] @ V[b] + kv[b]  (fp32, fused split epilogue -> wv pair)
        gemm_k<false, true><<<dim3(8, 2, B_), 256, 0, stream>>>(
            pb, KVb + D_, kv, nullptr, wv_h, wv_l, T_, T_, 2 * D_, D_,
            (long)T_ * T_, (long)T_ * 2 * D_, (long)T_ * D_, D_);

        // attention output projection
        mgemm_k<0, false, false><<<dim3(4, 32, 1), 256, 0, stream>>>(
            wv_h, wv_l, Wo_h, Wo_l, bo + i * D_,
            tmp, nullptr, nullptr, BT_, D_, D_, 0, 0, nullptr, nullptr, nullptr);

        // x = LN1(x + tmp)
        ln_res_k<<<BT_ / 4, 256, 0, stream>>>(x, tmp, ln1g + i * D_, ln1b + i * D_,
                                              x, x_h, x_l);

        // gating + routing
        zero_counts_k<<<1, 64, 0, stream>>>(counts);
        gate_k<<<BT_ / 4, 256, 0, stream>>>(x, gW + (long)i * D_ * E_, gb + i * E_,
                                            counts, toklist, tokslot, tokw);
        scan_k<<<1, 1, 0, stream>>>(counts, offsets);

        // MoE expert GEMMs (split MFMA)
        mgemm_k<1, true, true><<<dim3(16, 32, E_), 256, 0, stream>>>(
            x_h, x_l, e1_h, e1_l, eb1 + (long)i * E_ * FF_,
            nullptr, h_h, h_l, 0, D_, FF_,
            (long)FF_ * D_, FF_, counts, offsets, toklist);
        mgemm_k<2, false, false><<<dim3(4, 32, E_), 256, 0, stream>>>(
            h_h, h_l, e2_h, e2_l, eb2 + (long)i * E_ * D_,
            eo, nullptr, nullptr, 0, FF_, D_,
            (long)D_ * FF_, D_, counts, offsets, toklist);

        // x = LN2(x + w0*eo0 + w1*eo1)
        float* dst = (i == NL_ - 1) ? (float*)d_out : x;
        ln_moe_k<<<BT_ / 4, 256, 0, stream>>>(x, eo, tokslot, tokw, offsets,
                                              ln2g + i * D_, ln2b + i * D_,
                                              dst, x_h, x_l);
    }
}